// Round 6
// baseline (318.961 us; speedup 1.0000x reference)
//
#include <hip/hip_runtime.h>

// GraphConv GNN forward, MI355X — Round 21.
// R18 (+waves), R19 (slices), R20 (+ILP) all regressed => gathers are at the
// random-TRANSACTION ceiling; concurrency levers are exhausted. R21 keeps R17
// exactly (241.2us config) + ONE change: per-node CSR neighbor lists sorted
// ascending by src (insertion sort in buildgemm, thread=node, sdeg intact).
// Mechanism: all concurrent lanes at edge-iteration i access the i-th order
// statistic of ~16 uniform draws => instantaneous working set ~1-3MB (the
// i/16 quantile band), L2-resident per XCD, vs 6.4-12.8MB random before.
// Convoy locality: no extra work in hot loop, no launch changes.
// Read: -16..-31us => locality win; neutral => transaction ceiling confirmed
// from a 4th independent direction => structural floor.

#define NNODES 50000
#define NEDGES 800000
#define NGRAPH 64
#define NBUK 256                          // dst buckets
#define BSZ 196                           // nodes per bucket (196*256 >= 50000)
#define EPB (NEDGES / NBUK)               // 3125 edges per partition block
#define CVT_NB (NNODES * 128 / 4 / 256)   // 6250
#define PACK_NB (160 * 512 / 256)         // 320
#define PREP_NB (CVT_NB + PACK_NB + 1)    // 6571
#define RGRID ((NNODES + 127) / 128)      // 391 row blocks
#define RCHUNK ((RGRID + 7) / 8)          // 49 chunks of 8 row blocks
#define GB_SPLIT 196                      // gemm1 row blocks in partition launch
#define ZNB 32                            // zeroing blocks riding scan1 launch

typedef __attribute__((ext_vector_type(8))) __bf16 bf16x8;
typedef __attribute__((ext_vector_type(16))) float f32x16;

__device__ __forceinline__ unsigned short f2bf(float f) {
    unsigned u = __float_as_uint(f);
    u += 0x7fff + ((u >> 16) & 1);   // RNE
    return (unsigned short)(u >> 16);
}
__device__ __forceinline__ float bf2f(unsigned b) {
    return __uint_as_float(b << 16);
}

// async 16B global->LDS DMA; LDS dest is wave-uniform base + lane*16 [m104]
__device__ __forceinline__ void dma16(const void* g, void* l) {
    __builtin_amdgcn_global_load_lds(
        (const __attribute__((address_space(1))) void*)g,
        (__attribute__((address_space(3))) void*)l, 16, 0, 0);
}

// ---------------- prep body (cvt / weight pack / head fold) ------------------

__device__ __forceinline__ void pack32(const float* __restrict__ W, unsigned short* __restrict__ dst,
                                       int KS_tot, int ks0, int dcols, int ct0,
                                       int tl, int ksl, int lane, int j) {
    int k = ksl * 16 + ((lane >> 5) << 3) + j;
    int col = tl * 32 + (lane & 31);
    dst[(((size_t)(ct0 + tl) * KS_tot + (ks0 + ksl)) * 64 + lane) * 8 + j] = f2bf(W[k * dcols + col]);
}

__device__ void prep_body(int b, int tid,
                          const float* x, unsigned short* xbf,
                          const float* w1_rel, const float* w1_root,
                          const float* w2_rel, const float* w2_root,
                          const float* w3_rel, const float* w3_root,
                          unsigned short* pL1, unsigned short* pL2, unsigned short* pL3,
                          const float* w4_rel, const float* w4_root,
                          const float* b4, const float* head_w,
                          float* wr, float* wt, float* cbuf) {
    if (b < CVT_NB) {                       // fp32 -> bf16 of x
        int i = b * 256 + tid;
        float4 v = ((const float4*)x)[i];
        unsigned lo = (unsigned)f2bf(v.x) | ((unsigned)f2bf(v.y) << 16);
        unsigned hi = (unsigned)f2bf(v.z) | ((unsigned)f2bf(v.w) << 16);
        ((uint2*)xbf)[i] = make_uint2(lo, hi);
    } else if (b < CVT_NB + PACK_NB) {      // weight packing (32x32x16 B-frag order)
        int idx = (b - CVT_NB) * 256 + tid;
        int g = idx >> 9;
        int t = idx & 511;
        int lane = (t >> 3) & 63, j = t & 7;
        if (g < 16)       { int gl = g;       pack32(w1_rel,  pL1, 8,  0, 64,  0, gl / 8, gl % 8, lane, j); }
        else if (g < 32)  { int gl = g - 16;  pack32(w1_root, pL1, 8,  0, 64,  2, gl / 8, gl % 8, lane, j); }
        else if (g < 48)  { int gl = g - 32;  pack32(w2_rel,  pL2, 8,  0, 128, 0, gl / 4, gl % 4, lane, j); }
        else if (g < 64)  { int gl = g - 48;  pack32(w2_root, pL2, 8,  4, 128, 0, gl / 4, gl % 4, lane, j); }
        else if (g < 112) { int gl = g - 64;  pack32(w3_rel,  pL3, 16, 0, 192, 0, gl / 8, gl % 8, lane, j); }
        else              { int gl = g - 112; pack32(w3_root, pL3, 16, 8, 192, 0, gl / 8, gl % 8, lane, j); }
    } else {                                // head folding
        if (tid < 192) {
            float ar = 0.f, at = 0.f;
            for (int j = 0; j < 64; j++) {
                float hw = head_w[j];
                ar = fmaf(w4_rel[tid * 64 + j], hw, ar);
                at = fmaf(w4_root[tid * 64 + j], hw, at);
            }
            wr[tid] = ar;
            wt[tid] = at;
        } else if (tid == 192) {
            float c = 0.f;
            for (int j = 0; j < 64; j++) c = fmaf(b4[j], head_w[j], c);
            cbuf[0] = c;
        }
    }
}

// ---------------- fused hist + prep: disjoint block ranges, no fences --------

__global__ void __launch_bounds__(256) histprep_kernel(
    const int* __restrict__ edst, int* __restrict__ bcnt,
    const float* __restrict__ x, unsigned short* __restrict__ xbf,
    const float* __restrict__ w1_rel, const float* __restrict__ w1_root,
    const float* __restrict__ w2_rel, const float* __restrict__ w2_root,
    const float* __restrict__ w3_rel, const float* __restrict__ w3_root,
    unsigned short* __restrict__ pL1, unsigned short* __restrict__ pL2,
    unsigned short* __restrict__ pL3,
    const float* __restrict__ w4_rel, const float* __restrict__ w4_root,
    const float* __restrict__ b4, const float* __restrict__ head_w,
    float* __restrict__ wr, float* __restrict__ wt, float* __restrict__ cbuf)
{
    int tid = threadIdx.x, b = blockIdx.x;
    if (b < NBUK) {                          // histogram of edge chunk b
        __shared__ int h[NBUK];
        h[tid] = 0;
        __syncthreads();
        int end = (b + 1) * EPB;
        for (int i = b * EPB + tid; i < end; i += 256)
            atomicAdd(&h[edst[i] / BSZ], 1);
        __syncthreads();
        bcnt[tid * NBUK + b] = h[tid];
    } else {                                 // prep work, concurrent
        prep_body(b - NBUK, tid, x, xbf, w1_rel, w1_root, w2_rel, w2_root,
                  w3_rel, w3_root, pL1, pL2, pL3, w4_rel, w4_root, b4, head_w,
                  wr, wt, cbuf);
    }
}

// ---------------- scan1 + workspace zeroing (fused, independent ranges) ------

__global__ void scanzero_kernel(int* __restrict__ a, int* __restrict__ bsum, int n,
                                float4* __restrict__ zb, int zn16) {
    __shared__ int buf[256];
    int tid = threadIdx.x, b = blockIdx.x;
    if (b < NBUK) {                          // per-row local exclusive scan
        int i = b * 256 + tid;
        int v = (i < n) ? a[i] : 0;
        buf[tid] = v;
        __syncthreads();
        #pragma unroll
        for (int off = 1; off < 256; off <<= 1) {
            int t = (tid >= off) ? buf[tid - off] : 0;
            __syncthreads();
            buf[tid] += t;
            __syncthreads();
        }
        if (i < n) a[i] = buf[tid] - v;      // local exclusive (in-place)
        if (tid == 255) bsum[b] = buf[255];  // RAW row total (scan moved to consumers)
    } else {                                 // zero gsum/cnt/sbuf/tbuf region
        float4 zero = make_float4(0.f, 0.f, 0.f, 0.f);
        for (int i = (b - NBUK) * 256 + tid; i < zn16; i += ZNB * 256) zb[i] = zero;
    }
}

// ---------------- MFMA GEMM v5 body (LDS passed in by caller) ----------------

template<int KS, int NT, int NHALF, int ST, int KCH>
__device__ void gemm_body(
    unsigned short* sB, unsigned short* sA, int i,
    const unsigned short* __restrict__ A, const unsigned short* __restrict__ Wall,
    const float* __restrict__ bias, unsigned short* __restrict__ OUT,
    int ldo, int ocol0, int relu, int N,
    const float* __restrict__ wrp, const float* __restrict__ wtp,
    float* __restrict__ sb, float* __restrict__ tb)
{
    const int K = KS * 16;                  // elements (shorts) per row
    const int CPC = KCH * 2;                // 16B chunks per row per A-chunk

    int chunk = i / (8 * NHALF);
    int rem = i - chunk * (8 * NHALF);
    int halfsel = rem >> 3;
    int rowb = chunk * 8 + (rem & 7);       // halves of a rowb share blockIdx%8
    int rbase = rowb * 128;
    if (rbase >= N) return;                 // uniform per block

    int tid = threadIdx.x;
    int wave = tid >> 6, lane = tid & 63;
    int l32 = lane & 31, half = lane >> 5;
    const unsigned short* W = Wall + (size_t)halfsel * NT * KS * 512;

    // stage B once (linear)
    #pragma unroll
    for (int j = 0; j < NT * KS * 64 / 256; j++) {
        int p = j * 256 + wave * 64;        // wave-uniform base unit
        dma16(W + ((size_t)p + lane) * 8, sB + (size_t)p * 8);
    }

    f32x16 acc[NT];
    #pragma unroll
    for (int t = 0; t < NT; t++)
        #pragma unroll
        for (int r = 0; r < 16; r++) acc[t][r] = 0.f;

    int lr = wave * 32 + l32;               // local row of this lane's A frags

    for (int kb = 0; kb < KS; kb += KCH) {
        if (kb > 0) __syncthreads();        // protect sA overwrite
        // stage A chunk: 128 rows x KCH ks, XOR-swizzled 16B chunks
        #pragma unroll
        for (int j = 0; j < 128 * CPC / 256; j++) {
            int p = j * 256 + wave * 64 + lane;
            int r = p / CPC;
            int c = p - r * CPC;
            int cg = c ^ (r & (CPC - 1));
            dma16(A + (size_t)(rbase + r) * K + kb * 16 + cg * 8,
                  sA + (size_t)(j * 256 + wave * 64) * 8);
        }
        __syncthreads();                    // drains vmcnt before barrier
        #pragma unroll
        for (int l = 0; l < KCH; l++) {
            int cs = (l * 2 + half) ^ (lr & (CPC - 1));
            bf16x8 a = *(const bf16x8*)(sA + (size_t)lr * (KCH * 16) + cs * 8);
            int ks = kb + l;
            #pragma unroll
            for (int t = 0; t < NT; t++) {
                bf16x8 b = *(const bf16x8*)(sB + ((size_t)(t * KS + ks) * 64 + lane) * 8);
                acc[t] = __builtin_amdgcn_mfma_f32_32x32x16_bf16(a, b, acc[t], 0, 0, 0);
            }
        }
    }

    int wrbase = rbase + wave * 32;
    if constexpr (ST) {
        // fused L4 projection: partial s/t per row via shfl reduce + atomicAdd
        #pragma unroll
        for (int reg = 0; reg < 16; reg++) {
            int row = wrbase + (reg & 3) + 8 * (reg >> 2) + 4 * half;
            float sv = 0.f, tv = 0.f;
            #pragma unroll
            for (int t = 0; t < NT; t++) {
                int col = halfsel * NT * 32 + t * 32 + l32;
                float v = fmaxf(acc[t][reg] + bias[col], 0.f);
                sv = fmaf(v, wrp[col], sv);
                tv = fmaf(v, wtp[col], tv);
            }
            #pragma unroll
            for (int m = 1; m < 32; m <<= 1) {
                sv += __shfl_xor(sv, m, 64);
                tv += __shfl_xor(tv, m, 64);
            }
            if (l32 == 0 && row < N) {
                atomicAdd(&sb[row], sv);
                atomicAdd(&tb[row], tv);
            }
        }
    } else {
        #pragma unroll
        for (int t = 0; t < NT; t++) {
            int col = t * 32 + l32;
            float bi = bias ? bias[col] : 0.f;
            #pragma unroll
            for (int reg = 0; reg < 16; reg++) {
                int row = wrbase + (reg & 3) + 8 * (reg >> 2) + 4 * half;
                if (row < N) {
                    float v = acc[t][reg] + bi;
                    if (relu) v = fmaxf(v, 0.f);
                    OUT[(size_t)row * ldo + ocol0 + col] = f2bf(v);
                }
            }
        }
    }
}

// standalone GEMM kernel (L2, L3+L4)
template<int KS, int NT, int NHALF, int ST, int KCH>
__global__ __launch_bounds__(256) void gemm_v5(
    const unsigned short* __restrict__ A, const unsigned short* __restrict__ Wall,
    const float* __restrict__ bias, unsigned short* __restrict__ OUT,
    int ldo, int ocol0, int relu, int N,
    const float* __restrict__ wrp, const float* __restrict__ wtp,
    float* __restrict__ sb, float* __restrict__ tb)
{
    __shared__ __align__(16) unsigned short sB[NT * KS * 512];
    __shared__ __align__(16) unsigned short sA[128 * KCH * 16];
    gemm_body<KS, NT, NHALF, ST, KCH>(sB, sA, blockIdx.x, A, Wall, bias, OUT,
                                      ldo, ocol0, relu, N, wrp, wtp, sb, tb);
}

// ---------------- partition + gemm1(first half), fused block ranges ----------
// partition block: exclusive-scans raw bucket totals in LDS (replaces scan2);
// block 0 stores the scanned offsets for build. LDS overlaid with gemm's 64KB.

__global__ void __launch_bounds__(256) partgemm_kernel(
    const int* __restrict__ src, const int* __restrict__ dst,
    const int* __restrict__ cnt, const int* __restrict__ braw,
    int* __restrict__ sbsum, unsigned long long* __restrict__ pedge,
    const unsigned short* __restrict__ A, const unsigned short* __restrict__ W,
    unsigned short* __restrict__ OUT, int N)
{
    __shared__ __align__(16) unsigned short smem[32768];   // 64KB, overlaid
    int tid = threadIdx.x, b = blockIdx.x;
    if (b < NBUK) {
        int* lbase = (int*)smem;             // 256 ints
        int* sscan = lbase + 256;            // 256 ints
        int v = braw[tid];
        sscan[tid] = v;
        __syncthreads();
        #pragma unroll
        for (int off = 1; off < 256; off <<= 1) {
            int t = (tid >= off) ? sscan[tid - off] : 0;
            __syncthreads();
            sscan[tid] += t;
            __syncthreads();
        }
        int ex = sscan[tid] - v;             // exclusive bucket offset
        if (b == 0) sbsum[tid] = ex;         // for build_kernel
        lbase[tid] = cnt[tid * NBUK + b] + ex;
        __syncthreads();
        int end = (b + 1) * EPB;
        for (int i = b * EPB + tid; i < end; i += 256) {
            int s = src[i], d = dst[i];
            int pos = atomicAdd(&lbase[d / BSZ], 1);
            pedge[pos] = (unsigned long long)(unsigned)s | ((unsigned long long)(unsigned)d << 32);
        }
    } else {
        gemm_body<8, 4, 1, 0, 8>(smem, smem + 16384, b - NBUK,
                                 A, W, nullptr, OUT, 128, 0, 0, N,
                                 nullptr, nullptr, nullptr, nullptr);
    }
}

// ---------------- build + gemm1(second half), fused block ranges -------------
// After csr fill: per-node insertion sort ascending by src (thread = node).
// Convoy locality for the agg gathers; sdeg[] still holds degrees.

__global__ void __launch_bounds__(256) buildgemm_kernel(
    const unsigned long long* __restrict__ pedge, const int* __restrict__ sbsum,
    int* __restrict__ rp, int* __restrict__ csr,
    const unsigned short* __restrict__ A, const unsigned short* __restrict__ W,
    unsigned short* __restrict__ OUT, int N)
{
    __shared__ __align__(16) unsigned short smem[32768];   // 64KB, overlaid
    int tid = threadIdx.x, b = blockIdx.x;
    if (b < NBUK) {
        int* sdeg  = (int*)smem;
        int* sc    = sdeg + 256;
        int* sbase = sc + 256;
        int* sfill = sbase + 256;
        int node0 = b * BSZ;
        int ncnt = NNODES - node0;
        if (ncnt > BSZ) ncnt = BSZ;
        if (ncnt < 0) ncnt = 0;
        int seg0 = sbsum[b];
        int seg1 = (b + 1 < NBUK) ? sbsum[b + 1] : NEDGES;
        sdeg[tid] = 0;
        sfill[tid] = 0;
        __syncthreads();
        for (int i = seg0 + tid; i < seg1; i += 256)
            atomicAdd(&sdeg[(int)(pedge[i] >> 32) - node0], 1);
        __syncthreads();
        sc[tid] = sdeg[tid];
        __syncthreads();
        #pragma unroll
        for (int off = 1; off < 256; off <<= 1) {
            int t = (tid >= off) ? sc[tid - off] : 0;
            __syncthreads();
            sc[tid] += t;
            __syncthreads();
        }
        sbase[tid] = sc[tid] - sdeg[tid];    // exclusive within bucket
        if (tid < ncnt) rp[node0 + tid] = seg0 + sbase[tid];
        if (b == NBUK - 1 && tid == 0) rp[NNODES] = NEDGES;
        __syncthreads();
        for (int i = seg0 + tid; i < seg1; i += 256) {
            unsigned long long p = pedge[i];
            int d = (int)(p >> 32) - node0;
            int pos = atomicAdd(&sfill[d], 1);
            csr[seg0 + sbase[d] + pos] = (int)(p & 0xffffffffu);
        }
        __syncthreads();
        if (tid < ncnt) {                    // sort node tid's segment by src
            int lo = seg0 + sbase[tid];
            int hi = lo + sdeg[tid];
            for (int i2 = lo + 1; i2 < hi; i2++) {
                int v2 = csr[i2];
                int j2 = i2 - 1;
                while (j2 >= lo && csr[j2] > v2) { csr[j2 + 1] = csr[j2]; j2--; }
                csr[j2 + 1] = v2;
            }
        }
    } else {
        gemm_body<8, 4, 1, 0, 8>(smem, smem + 16384, GB_SPLIT + (b - NBUK),
                                 A, W, nullptr, OUT, 128, 0, 0, N,
                                 nullptr, nullptr, nullptr, nullptr);
    }
}

// ---------------- bf16 neighbor-sum via CSR gather (R17 exact) ---------------

__device__ __forceinline__ void acc8(float* a, uint4 u) {
    a[0] += bf2f(u.x & 0xffffu); a[1] += bf2f(u.x >> 16);
    a[2] += bf2f(u.y & 0xffffu); a[3] += bf2f(u.y >> 16);
    a[4] += bf2f(u.z & 0xffffu); a[5] += bf2f(u.z >> 16);
    a[6] += bf2f(u.w & 0xffffu); a[7] += bf2f(u.w >> 16);
}

template<int LPF, int SUBS>
__global__ void agg_kernel_v4(const unsigned short* __restrict__ X, int ldx,
                              const int* __restrict__ rp, const int* __restrict__ csr,
                              const unsigned short* __restrict__ root, int ldr,
                              const float* __restrict__ bias, int relu,
                              unsigned short* __restrict__ OUT, int ldo, int N) {
    int t = blockIdx.x * blockDim.x + threadIdx.x;
    int node = t / (SUBS * LPF);
    int r = t % (SUBS * LPF);
    int sub = r / LPF;
    int sl = r % LPF;
    if (node >= N) return;
    float a[8] = {0.f, 0.f, 0.f, 0.f, 0.f, 0.f, 0.f, 0.f};
    int e0 = rp[node], e1 = rp[node + 1];
    const unsigned short* xb = X + 8 * sl;
    int e = e0 + sub;
    for (; e + 3 * SUBS < e1; e += 4 * SUBS) {    // 4 independent gathers in flight
        int s0 = csr[e], s1 = csr[e + SUBS], s2 = csr[e + 2 * SUBS], s3 = csr[e + 3 * SUBS];
        uint4 u0 = *(const uint4*)(xb + (size_t)s0 * ldx);
        uint4 u1 = *(const uint4*)(xb + (size_t)s1 * ldx);
        uint4 u2 = *(const uint4*)(xb + (size_t)s2 * ldx);
        uint4 u3 = *(const uint4*)(xb + (size_t)s3 * ldx);
        acc8(a, u0); acc8(a, u1); acc8(a, u2); acc8(a, u3);
    }
    for (; e < e1; e += SUBS) {
        uint4 u = *(const uint4*)(xb + (size_t)csr[e] * ldx);
        acc8(a, u);
    }
    #pragma unroll
    for (int m = LPF; m < SUBS * LPF; m <<= 1)
        #pragma unroll
        for (int i = 0; i < 8; i++) a[i] += __shfl_xor(a[i], m, 64);
    if (sub == 0) {
        if (root) {
            uint4 u = *(const uint4*)(root + (size_t)node * ldr + 8 * sl);
            acc8(a, u);
        }
        if (bias) {
            float4 b0 = *(const float4*)(bias + 8 * sl);
            float4 b1 = *(const float4*)(bias + 8 * sl + 4);
            a[0] += b0.x; a[1] += b0.y; a[2] += b0.z; a[3] += b0.w;
            a[4] += b1.x; a[5] += b1.y; a[6] += b1.z; a[7] += b1.w;
        }
        if (relu) {
            #pragma unroll
            for (int i = 0; i < 8; i++) a[i] = fmaxf(a[i], 0.f);
        }
        uint4 o;
        o.x = (unsigned)f2bf(a[0]) | ((unsigned)f2bf(a[1]) << 16);
        o.y = (unsigned)f2bf(a[2]) | ((unsigned)f2bf(a[3]) << 16);
        o.z = (unsigned)f2bf(a[4]) | ((unsigned)f2bf(a[5]) << 16);
        o.w = (unsigned)f2bf(a[6]) | ((unsigned)f2bf(a[7]) << 16);
        *(uint4*)(OUT + (size_t)node * ldo + 8 * sl) = o;
    }
}

// ---------------- pool + head (R17 shape) ------------------------------------

__global__ void aggpool_kernel(const float* __restrict__ s, const float* __restrict__ t,
                               const int* __restrict__ rp, const int* __restrict__ csr,
                               const int* __restrict__ batch, float* __restrict__ gsum,
                               int* __restrict__ cnt, int N) {
    __shared__ float ls[NGRAPH];
    __shared__ int lc[NGRAPH];
    int tid = threadIdx.x;
    if (tid < NGRAPH) { ls[tid] = 0.f; lc[tid] = 0; }
    __syncthreads();
    int n = blockIdx.x * blockDim.x + tid;
    if (n < N) {
        float a = 0.f;
        int e = rp[n], e1 = rp[n + 1];
        for (; e + 3 < e1; e += 4) {
            int s0 = csr[e], s1 = csr[e + 1], s2 = csr[e + 2], s3 = csr[e + 3];
            a += s[s0] + s[s1] + s[s2] + s[s3];
        }
        for (; e < e1; e++) a += s[csr[e]];
        int g = batch[n];
        atomicAdd(&ls[g], a + t[n]);
        atomicAdd(&lc[g], 1);
    }
    __syncthreads();
    if (tid < NGRAPH && lc[tid] > 0) {
        atomicAdd(&gsum[tid], ls[tid]);
        atomicAdd(&cnt[tid], lc[tid]);
    }
}

__global__ void final_kernel(const float* __restrict__ gsum, const int* __restrict__ cnt,
                             const float* __restrict__ cbuf, const float* __restrict__ head_b,
                             float* __restrict__ out) {
    int g = threadIdx.x;
    if (g < NGRAPH) {
        float c = (float)(cnt[g] > 0 ? cnt[g] : 1);
        out[g] = gsum[g] / c + cbuf[0] + head_b[0];
    }
}

// ---------------- launch ----------------

extern "C" void kernel_launch(void* const* d_in, const int* in_sizes, int n_in,
                              void* d_out, int out_size, void* d_ws, size_t ws_size,
                              hipStream_t stream) {
    const float* x       = (const float*)d_in[0];
    const int*   edge    = (const int*)d_in[1];
    const int*   batch   = (const int*)d_in[2];
    const float* w1_rel  = (const float*)d_in[3];
    const float* w1_root = (const float*)d_in[4];
    const float* b1      = (const float*)d_in[5];
    const float* w2_rel  = (const float*)d_in[6];
    const float* w2_root = (const float*)d_in[7];
    const float* b2      = (const float*)d_in[8];
    const float* w3_rel  = (const float*)d_in[9];
    const float* w3_root = (const float*)d_in[10];
    const float* b3      = (const float*)d_in[11];
    const float* w4_rel  = (const float*)d_in[12];
    const float* w4_root = (const float*)d_in[13];
    const float* b4      = (const float*)d_in[14];
    const float* head_w  = (const float*)d_in[15];
    const float* head_b  = (const float*)d_in[16];
    float* out = (float*)d_out;

    const int N = NNODES, E = NEDGES;
    const int* esrc = edge;
    const int* edst = edge + E;

    char* ws = (char*)d_ws;
    size_t off = 0;
    auto alloc = [&](size_t bytes) -> char* {
        char* p = ws + off;
        off = (off + bytes + 255) & ~(size_t)255;
        return p;
    };
    // zeroed region first (one fused zeroing pass): gsum, cnt, sbuf, tbuf
    float* gsum  = (float*)alloc(NGRAPH * 4);
    int*   cnt   = (int*)alloc(NGRAPH * 4);
    float* sbuf  = (float*)alloc((size_t)N * 4);
    float* tbuf  = (float*)alloc((size_t)N * 4);
    size_t zero_bytes = off;                               // 256-aligned, /16 ok
    int*   bcnt  = (int*)alloc((size_t)NBUK * NBUK * 4);   // bucket x block counts
    int*   bsum  = (int*)alloc(256 * 4);                   // RAW bucket totals
    int*   sbsum = (int*)alloc(256 * 4);                   // scanned bucket offsets
    int*   rp    = (int*)alloc((size_t)(N + 1) * 4);
    int*   csr   = (int*)alloc((size_t)E * 4);
    unsigned long long* pedge = (unsigned long long*)alloc((size_t)E * 8);
    unsigned short* xbf    = (unsigned short*)alloc((size_t)N * 128 * 2);
    unsigned short* z1     = (unsigned short*)alloc((size_t)N * 128 * 2);  // [x@w1_rel | x@w1_root]
    unsigned short* combo2 = (unsigned short*)alloc((size_t)N * 128 * 2);  // [agg2 | h1]
    unsigned short* combo3 = (unsigned short*)alloc((size_t)N * 256 * 2);  // [agg3 | h2]
    unsigned short* pL1    = (unsigned short*)alloc(4 * 8 * 512 * 2);      // also DMA overrun slack
    unsigned short* pL2    = (unsigned short*)alloc(4 * 8 * 512 * 2);
    unsigned short* pL3    = (unsigned short*)alloc(6 * 16 * 512 * 2);
    float* wr    = (float*)alloc(192 * 4);
    float* wt    = (float*)alloc(192 * 4);
    float* cbuf  = (float*)alloc(4);
    (void)ws_size;

    const int TB = 256;

    // CSR build + prep; gemm1 overlapped with partition/build (disjoint ranges)
    histprep_kernel<<<NBUK + PREP_NB, 256, 0, stream>>>(
        edst, bcnt, x, xbf, w1_rel, w1_root, w2_rel, w2_root, w3_rel, w3_root,
        pL1, pL2, pL3, w4_rel, w4_root, b4, head_w, wr, wt, cbuf);
    scanzero_kernel<<<NBUK + ZNB, 256, 0, stream>>>(
        bcnt, bsum, NBUK * NBUK, (float4*)ws, (int)(zero_bytes / 16));
    partgemm_kernel<<<NBUK + GB_SPLIT, 256, 0, stream>>>(
        esrc, edst, bcnt, bsum, sbsum, pedge, xbf, pL1, z1, N);
    buildgemm_kernel<<<NBUK + (RCHUNK * 8 - GB_SPLIT), 256, 0, stream>>>(
        pedge, sbsum, rp, csr, xbf, pL1, z1, N);

    // h1 = relu( nbrsum(z1[:,:64]) + z1[:,64:] + b1 ) -> combo2[:,64:]
    agg_kernel_v4<8, 2><<<(N * 16 + TB - 1) / TB, TB, 0, stream>>>(z1, 128, rp, csr,
                                                                   z1 + 64, 128, b1, 1, combo2 + 64, 128, N);
    // agg2 = nbrsum(h1) -> combo2[:,:64]
    agg_kernel_v4<8, 2><<<(N * 16 + TB - 1) / TB, TB, 0, stream>>>(combo2 + 64, 128, rp, csr,
                                                                   nullptr, 0, nullptr, 0, combo2, 128, N);
    // L2: h2 = relu(combo2 @ [w2_rel; w2_root] + b2) -> combo3[:,128:]
    gemm_v5<8, 4, 1, 0, 8><<<RCHUNK * 8, 256, 0, stream>>>(
        combo2, pL2, b2, combo3, 256, 128, 1, N, nullptr, nullptr, nullptr, nullptr);
    // agg3 = nbrsum(h2) -> combo3[:,:128]
    agg_kernel_v4<16, 2><<<(N * 32 + TB - 1) / TB, TB, 0, stream>>>(combo3 + 128, 256, rp, csr,
                                                                    nullptr, 0, nullptr, 0, combo3, 256, N);
    // L3 + fused L4 projection (K=256, col-halved, A chunked 16KB, LDS 64KB)
    gemm_v5<16, 3, 2, 1, 4><<<RCHUNK * 8 * 2, 256, 0, stream>>>(
        combo3, pL3, b3, nullptr, 0, 0, 0, N, wr, wt, sbuf, tbuf);

    // pool + head
    aggpool_kernel<<<(N + TB - 1) / TB, TB, 0, stream>>>(sbuf, tbuf, rp, csr, batch, gsum, cnt, N);
    final_kernel<<<1, 64, 0, stream>>>(gsum, cnt, cbuf, head_b, out);
}

// Round 7
// 303.037 us; speedup vs baseline: 1.0525x; 1.0525x over previous
//
#include <hip/hip_runtime.h>

// GraphConv GNN forward, MI355X — Round 22.
// R18/R19/R20/R21: more waves, col-slices, deeper ILP, sorted lists — all
// null/negative for the aggs. Diagnosis: L2 CAPACITY. Tables 6.4-12.8MB vs
// 4MB/XCD L2 => gathers miss to L3 at random-transaction cost.
// R22: phase-partitioned gathers across SEPARATE LAUNCHES (launches serialize
// on-stream, unlike R19's concurrent blockIdx slices):
//  - build partitions each node's CSR list into 4 src-quartiles (atomic
//    counters, O(E), no sort; rpm[3N] holds per-node quartile boundaries)
//  - agg1/agg2: 2 launches each over quartile pairs (3.2MB table/phase < L2)
//  - agg3: 4 launches (3.2MB/phase); fp32 partials between phases via
//    nontemporal ld/st in dead xbf(+z1) memory (no new allocation)
// Read: ~185-210us => capacity theory confirmed; ~245-255 => per-transaction
// cost independent of hit level => aggs structurally floored.

#define NNODES 50000
#define NEDGES 800000
#define NGRAPH 64
#define NBUK 256                          // dst buckets
#define BSZ 196                           // nodes per bucket (196*256 >= 50000)
#define EPB (NEDGES / NBUK)               // 3125 edges per partition block
#define CVT_NB (NNODES * 128 / 4 / 256)   // 6250
#define PACK_NB (160 * 512 / 256)         // 320
#define PREP_NB (CVT_NB + PACK_NB + 1)    // 6571
#define RGRID ((NNODES + 127) / 128)      // 391 row blocks
#define RCHUNK ((RGRID + 7) / 8)          // 49 chunks of 8 row blocks
#define GB_SPLIT 196                      // gemm1 row blocks in partition launch
#define ZNB 32                            // zeroing blocks riding scan1 launch
#define QS ((NNODES + 3) / 4)             // 12500: src quartile size

typedef __attribute__((ext_vector_type(8))) __bf16 bf16x8;
typedef __attribute__((ext_vector_type(16))) float f32x16;
typedef __attribute__((ext_vector_type(4))) float f32x4v;

__device__ __forceinline__ unsigned short f2bf(float f) {
    unsigned u = __float_as_uint(f);
    u += 0x7fff + ((u >> 16) & 1);   // RNE
    return (unsigned short)(u >> 16);
}
__device__ __forceinline__ float bf2f(unsigned b) {
    return __uint_as_float(b << 16);
}

// async 16B global->LDS DMA; LDS dest is wave-uniform base + lane*16 [m104]
__device__ __forceinline__ void dma16(const void* g, void* l) {
    __builtin_amdgcn_global_load_lds(
        (const __attribute__((address_space(1))) void*)g,
        (__attribute__((address_space(3))) void*)l, 16, 0, 0);
}

// ---------------- prep body (cvt / weight pack / head fold) ------------------

__device__ __forceinline__ void pack32(const float* __restrict__ W, unsigned short* __restrict__ dst,
                                       int KS_tot, int ks0, int dcols, int ct0,
                                       int tl, int ksl, int lane, int j) {
    int k = ksl * 16 + ((lane >> 5) << 3) + j;
    int col = tl * 32 + (lane & 31);
    dst[(((size_t)(ct0 + tl) * KS_tot + (ks0 + ksl)) * 64 + lane) * 8 + j] = f2bf(W[k * dcols + col]);
}

__device__ void prep_body(int b, int tid,
                          const float* x, unsigned short* xbf,
                          const float* w1_rel, const float* w1_root,
                          const float* w2_rel, const float* w2_root,
                          const float* w3_rel, const float* w3_root,
                          unsigned short* pL1, unsigned short* pL2, unsigned short* pL3,
                          const float* w4_rel, const float* w4_root,
                          const float* b4, const float* head_w,
                          float* wr, float* wt, float* cbuf) {
    if (b < CVT_NB) {                       // fp32 -> bf16 of x
        int i = b * 256 + tid;
        float4 v = ((const float4*)x)[i];
        unsigned lo = (unsigned)f2bf(v.x) | ((unsigned)f2bf(v.y) << 16);
        unsigned hi = (unsigned)f2bf(v.z) | ((unsigned)f2bf(v.w) << 16);
        ((uint2*)xbf)[i] = make_uint2(lo, hi);
    } else if (b < CVT_NB + PACK_NB) {      // weight packing (32x32x16 B-frag order)
        int idx = (b - CVT_NB) * 256 + tid;
        int g = idx >> 9;
        int t = idx & 511;
        int lane = (t >> 3) & 63, j = t & 7;
        if (g < 16)       { int gl = g;       pack32(w1_rel,  pL1, 8,  0, 64,  0, gl / 8, gl % 8, lane, j); }
        else if (g < 32)  { int gl = g - 16;  pack32(w1_root, pL1, 8,  0, 64,  2, gl / 8, gl % 8, lane, j); }
        else if (g < 48)  { int gl = g - 32;  pack32(w2_rel,  pL2, 8,  0, 128, 0, gl / 4, gl % 4, lane, j); }
        else if (g < 64)  { int gl = g - 48;  pack32(w2_root, pL2, 8,  4, 128, 0, gl / 4, gl % 4, lane, j); }
        else if (g < 112) { int gl = g - 64;  pack32(w3_rel,  pL3, 16, 0, 192, 0, gl / 8, gl % 8, lane, j); }
        else              { int gl = g - 112; pack32(w3_root, pL3, 16, 8, 192, 0, gl / 8, gl % 8, lane, j); }
    } else {                                // head folding
        if (tid < 192) {
            float ar = 0.f, at = 0.f;
            for (int j = 0; j < 64; j++) {
                float hw = head_w[j];
                ar = fmaf(w4_rel[tid * 64 + j], hw, ar);
                at = fmaf(w4_root[tid * 64 + j], hw, at);
            }
            wr[tid] = ar;
            wt[tid] = at;
        } else if (tid == 192) {
            float c = 0.f;
            for (int j = 0; j < 64; j++) c = fmaf(b4[j], head_w[j], c);
            cbuf[0] = c;
        }
    }
}

// ---------------- fused hist + prep: disjoint block ranges, no fences --------

__global__ void __launch_bounds__(256) histprep_kernel(
    const int* __restrict__ edst, int* __restrict__ bcnt,
    const float* __restrict__ x, unsigned short* __restrict__ xbf,
    const float* __restrict__ w1_rel, const float* __restrict__ w1_root,
    const float* __restrict__ w2_rel, const float* __restrict__ w2_root,
    const float* __restrict__ w3_rel, const float* __restrict__ w3_root,
    unsigned short* __restrict__ pL1, unsigned short* __restrict__ pL2,
    unsigned short* __restrict__ pL3,
    const float* __restrict__ w4_rel, const float* __restrict__ w4_root,
    const float* __restrict__ b4, const float* __restrict__ head_w,
    float* __restrict__ wr, float* __restrict__ wt, float* __restrict__ cbuf)
{
    int tid = threadIdx.x, b = blockIdx.x;
    if (b < NBUK) {                          // histogram of edge chunk b
        __shared__ int h[NBUK];
        h[tid] = 0;
        __syncthreads();
        int end = (b + 1) * EPB;
        for (int i = b * EPB + tid; i < end; i += 256)
            atomicAdd(&h[edst[i] / BSZ], 1);
        __syncthreads();
        bcnt[tid * NBUK + b] = h[tid];
    } else {                                 // prep work, concurrent
        prep_body(b - NBUK, tid, x, xbf, w1_rel, w1_root, w2_rel, w2_root,
                  w3_rel, w3_root, pL1, pL2, pL3, w4_rel, w4_root, b4, head_w,
                  wr, wt, cbuf);
    }
}

// ---------------- scan1 + workspace zeroing (fused, independent ranges) ------

__global__ void scanzero_kernel(int* __restrict__ a, int* __restrict__ bsum, int n,
                                float4* __restrict__ zb, int zn16) {
    __shared__ int buf[256];
    int tid = threadIdx.x, b = blockIdx.x;
    if (b < NBUK) {                          // per-row local exclusive scan
        int i = b * 256 + tid;
        int v = (i < n) ? a[i] : 0;
        buf[tid] = v;
        __syncthreads();
        #pragma unroll
        for (int off = 1; off < 256; off <<= 1) {
            int t = (tid >= off) ? buf[tid - off] : 0;
            __syncthreads();
            buf[tid] += t;
            __syncthreads();
        }
        if (i < n) a[i] = buf[tid] - v;      // local exclusive (in-place)
        if (tid == 255) bsum[b] = buf[255];  // RAW row total (scan moved to consumers)
    } else {                                 // zero gsum/cnt/sbuf/tbuf region
        float4 zero = make_float4(0.f, 0.f, 0.f, 0.f);
        for (int i = (b - NBUK) * 256 + tid; i < zn16; i += ZNB * 256) zb[i] = zero;
    }
}

// ---------------- MFMA GEMM v5 body (LDS passed in by caller) ----------------

template<int KS, int NT, int NHALF, int ST, int KCH>
__device__ void gemm_body(
    unsigned short* sB, unsigned short* sA, int i,
    const unsigned short* __restrict__ A, const unsigned short* __restrict__ Wall,
    const float* __restrict__ bias, unsigned short* __restrict__ OUT,
    int ldo, int ocol0, int relu, int N,
    const float* __restrict__ wrp, const float* __restrict__ wtp,
    float* __restrict__ sb, float* __restrict__ tb)
{
    const int K = KS * 16;                  // elements (shorts) per row
    const int CPC = KCH * 2;                // 16B chunks per row per A-chunk

    int chunk = i / (8 * NHALF);
    int rem = i - chunk * (8 * NHALF);
    int halfsel = rem >> 3;
    int rowb = chunk * 8 + (rem & 7);       // halves of a rowb share blockIdx%8
    int rbase = rowb * 128;
    if (rbase >= N) return;                 // uniform per block

    int tid = threadIdx.x;
    int wave = tid >> 6, lane = tid & 63;
    int l32 = lane & 31, half = lane >> 5;
    const unsigned short* W = Wall + (size_t)halfsel * NT * KS * 512;

    // stage B once (linear)
    #pragma unroll
    for (int j = 0; j < NT * KS * 64 / 256; j++) {
        int p = j * 256 + wave * 64;        // wave-uniform base unit
        dma16(W + ((size_t)p + lane) * 8, sB + (size_t)p * 8);
    }

    f32x16 acc[NT];
    #pragma unroll
    for (int t = 0; t < NT; t++)
        #pragma unroll
        for (int r = 0; r < 16; r++) acc[t][r] = 0.f;

    int lr = wave * 32 + l32;               // local row of this lane's A frags

    for (int kb = 0; kb < KS; kb += KCH) {
        if (kb > 0) __syncthreads();        // protect sA overwrite
        // stage A chunk: 128 rows x KCH ks, XOR-swizzled 16B chunks
        #pragma unroll
        for (int j = 0; j < 128 * CPC / 256; j++) {
            int p = j * 256 + wave * 64 + lane;
            int r = p / CPC;
            int c = p - r * CPC;
            int cg = c ^ (r & (CPC - 1));
            dma16(A + (size_t)(rbase + r) * K + kb * 16 + cg * 8,
                  sA + (size_t)(j * 256 + wave * 64) * 8);
        }
        __syncthreads();                    // drains vmcnt before barrier
        #pragma unroll
        for (int l = 0; l < KCH; l++) {
            int cs = (l * 2 + half) ^ (lr & (CPC - 1));
            bf16x8 a = *(const bf16x8*)(sA + (size_t)lr * (KCH * 16) + cs * 8);
            int ks = kb + l;
            #pragma unroll
            for (int t = 0; t < NT; t++) {
                bf16x8 b = *(const bf16x8*)(sB + ((size_t)(t * KS + ks) * 64 + lane) * 8);
                acc[t] = __builtin_amdgcn_mfma_f32_32x32x16_bf16(a, b, acc[t], 0, 0, 0);
            }
        }
    }

    int wrbase = rbase + wave * 32;
    if constexpr (ST) {
        // fused L4 projection: partial s/t per row via shfl reduce + atomicAdd
        #pragma unroll
        for (int reg = 0; reg < 16; reg++) {
            int row = wrbase + (reg & 3) + 8 * (reg >> 2) + 4 * half;
            float sv = 0.f, tv = 0.f;
            #pragma unroll
            for (int t = 0; t < NT; t++) {
                int col = halfsel * NT * 32 + t * 32 + l32;
                float v = fmaxf(acc[t][reg] + bias[col], 0.f);
                sv = fmaf(v, wrp[col], sv);
                tv = fmaf(v, wtp[col], tv);
            }
            #pragma unroll
            for (int m = 1; m < 32; m <<= 1) {
                sv += __shfl_xor(sv, m, 64);
                tv += __shfl_xor(tv, m, 64);
            }
            if (l32 == 0 && row < N) {
                atomicAdd(&sb[row], sv);
                atomicAdd(&tb[row], tv);
            }
        }
    } else {
        #pragma unroll
        for (int t = 0; t < NT; t++) {
            int col = t * 32 + l32;
            float bi = bias ? bias[col] : 0.f;
            #pragma unroll
            for (int reg = 0; reg < 16; reg++) {
                int row = wrbase + (reg & 3) + 8 * (reg >> 2) + 4 * half;
                if (row < N) {
                    float v = acc[t][reg] + bi;
                    if (relu) v = fmaxf(v, 0.f);
                    OUT[(size_t)row * ldo + ocol0 + col] = f2bf(v);
                }
            }
        }
    }
}

// standalone GEMM kernel (L2, L3+L4)
template<int KS, int NT, int NHALF, int ST, int KCH>
__global__ __launch_bounds__(256) void gemm_v5(
    const unsigned short* __restrict__ A, const unsigned short* __restrict__ Wall,
    const float* __restrict__ bias, unsigned short* __restrict__ OUT,
    int ldo, int ocol0, int relu, int N,
    const float* __restrict__ wrp, const float* __restrict__ wtp,
    float* __restrict__ sb, float* __restrict__ tb)
{
    __shared__ __align__(16) unsigned short sB[NT * KS * 512];
    __shared__ __align__(16) unsigned short sA[128 * KCH * 16];
    gemm_body<KS, NT, NHALF, ST, KCH>(sB, sA, blockIdx.x, A, Wall, bias, OUT,
                                      ldo, ocol0, relu, N, wrp, wtp, sb, tb);
}

// ---------------- partition + gemm1(first half), fused block ranges ----------

__global__ void __launch_bounds__(256) partgemm_kernel(
    const int* __restrict__ src, const int* __restrict__ dst,
    const int* __restrict__ cnt, const int* __restrict__ braw,
    int* __restrict__ sbsum, unsigned long long* __restrict__ pedge,
    const unsigned short* __restrict__ A, const unsigned short* __restrict__ W,
    unsigned short* __restrict__ OUT, int N)
{
    __shared__ __align__(16) unsigned short smem[32768];   // 64KB, overlaid
    int tid = threadIdx.x, b = blockIdx.x;
    if (b < NBUK) {
        int* lbase = (int*)smem;             // 256 ints
        int* sscan = lbase + 256;            // 256 ints
        int v = braw[tid];
        sscan[tid] = v;
        __syncthreads();
        #pragma unroll
        for (int off = 1; off < 256; off <<= 1) {
            int t = (tid >= off) ? sscan[tid - off] : 0;
            __syncthreads();
            sscan[tid] += t;
            __syncthreads();
        }
        int ex = sscan[tid] - v;             // exclusive bucket offset
        if (b == 0) sbsum[tid] = ex;         // for build_kernel
        lbase[tid] = cnt[tid * NBUK + b] + ex;
        __syncthreads();
        int end = (b + 1) * EPB;
        for (int i = b * EPB + tid; i < end; i += 256) {
            int s = src[i], d = dst[i];
            int pos = atomicAdd(&lbase[d / BSZ], 1);
            pedge[pos] = (unsigned long long)(unsigned)s | ((unsigned long long)(unsigned)d << 32);
        }
    } else {
        gemm_body<8, 4, 1, 0, 8>(smem, smem + 16384, b - NBUK,
                                 A, W, nullptr, OUT, 128, 0, 0, N,
                                 nullptr, nullptr, nullptr, nullptr);
    }
}

// ---------------- build + gemm1(second half), fused block ranges -------------
// CSR fill partitioned into 4 src-quartiles per node (4 atomic counters).
// rpm[3*node+k] = end of quartile k within node's segment.

__global__ void __launch_bounds__(256) buildgemm_kernel(
    const unsigned long long* __restrict__ pedge, const int* __restrict__ sbsum,
    int* __restrict__ rp, int* __restrict__ rpm, int* __restrict__ csr,
    const unsigned short* __restrict__ A, const unsigned short* __restrict__ W,
    unsigned short* __restrict__ OUT, int N)
{
    __shared__ __align__(16) unsigned short smem[32768];   // 64KB, overlaid
    int tid = threadIdx.x, b = blockIdx.x;
    if (b < NBUK) {
        int* sdeg4  = (int*)smem;            // [256][4] quartile counts -> bases
        int* sfill4 = sdeg4 + 1024;          // [256][4]
        int* sc     = sfill4 + 1024;         // 256
        int* sbase  = sc + 256;              // 256
        int node0 = b * BSZ;
        int ncnt = NNODES - node0;
        if (ncnt > BSZ) ncnt = BSZ;
        if (ncnt < 0) ncnt = 0;
        int seg0 = sbsum[b];
        int seg1 = (b + 1 < NBUK) ? sbsum[b + 1] : NEDGES;
        #pragma unroll
        for (int k = 0; k < 4; k++) {
            sdeg4[tid * 4 + k] = 0;
            sfill4[tid * 4 + k] = 0;
        }
        __syncthreads();
        for (int i = seg0 + tid; i < seg1; i += 256) {
            unsigned long long p = pedge[i];
            int d = (int)(p >> 32) - node0;
            int s = (int)(p & 0xffffffffu);
            atomicAdd(&sdeg4[d * 4 + s / QS], 1);
        }
        __syncthreads();
        int c0 = sdeg4[tid * 4 + 0], c1 = sdeg4[tid * 4 + 1];
        int c2 = sdeg4[tid * 4 + 2], c3 = sdeg4[tid * 4 + 3];
        int tot = c0 + c1 + c2 + c3;
        sc[tid] = tot;
        __syncthreads();
        #pragma unroll
        for (int off = 1; off < 256; off <<= 1) {
            int t = (tid >= off) ? sc[tid - off] : 0;
            __syncthreads();
            sc[tid] += t;
            __syncthreads();
        }
        sbase[tid] = sc[tid] - tot;          // exclusive within bucket
        int base = seg0 + sbase[tid];
        if (tid < ncnt) {
            rp[node0 + tid] = base;
            rpm[3 * (node0 + tid) + 0] = base + c0;
            rpm[3 * (node0 + tid) + 1] = base + c0 + c1;
            rpm[3 * (node0 + tid) + 2] = base + c0 + c1 + c2;
        }
        if (b == NBUK - 1 && tid == 0) rp[NNODES] = NEDGES;
        // counts -> per-quartile fill bases (in place)
        sdeg4[tid * 4 + 0] = base;
        sdeg4[tid * 4 + 1] = base + c0;
        sdeg4[tid * 4 + 2] = base + c0 + c1;
        sdeg4[tid * 4 + 3] = base + c0 + c1 + c2;
        __syncthreads();
        for (int i = seg0 + tid; i < seg1; i += 256) {
            unsigned long long p = pedge[i];
            int d = (int)(p >> 32) - node0;
            int s = (int)(p & 0xffffffffu);
            int q = d * 4 + s / QS;
            int pos = sdeg4[q] + atomicAdd(&sfill4[q], 1);
            csr[pos] = s;
        }
    } else {
        gemm_body<8, 4, 1, 0, 8>(smem, smem + 16384, GB_SPLIT + (b - NBUK),
                                 A, W, nullptr, OUT, 128, 0, 0, N,
                                 nullptr, nullptr, nullptr, nullptr);
    }
}

// ---------------- bf16 neighbor-sum, quartile-phased (L2-resident table) -----
// One launch handles src quartiles [qa,qb): table slice <= 3.2MB fits each
// XCD's 4MB L2. fp32 partials (nontemporal) carry the running sum between
// launches; the final launch adds root/bias and writes bf16.

__device__ __forceinline__ void acc8(float* a, uint4 u) {
    a[0] += bf2f(u.x & 0xffffu); a[1] += bf2f(u.x >> 16);
    a[2] += bf2f(u.y & 0xffffu); a[3] += bf2f(u.y >> 16);
    a[4] += bf2f(u.z & 0xffffu); a[5] += bf2f(u.z >> 16);
    a[6] += bf2f(u.w & 0xffffu); a[7] += bf2f(u.w >> 16);
}

template<int LPF, int SUBS>
__global__ void agg_kernel_v7(const unsigned short* __restrict__ X, int ldx,
                              const int* __restrict__ rp, const int* __restrict__ rpm,
                              const int* __restrict__ csr, int qa, int qb,
                              const float* __restrict__ pin, float* __restrict__ pout,
                              const unsigned short* __restrict__ root, int ldr,
                              const float* __restrict__ bias, int relu,
                              unsigned short* __restrict__ OUT, int ldo, int N) {
    int t = blockIdx.x * blockDim.x + threadIdx.x;
    int node = t / (SUBS * LPF);
    int r = t % (SUBS * LPF);
    int sub = r / LPF;
    int sl = r % LPF;
    if (node >= N) return;
    float a[8] = {0.f, 0.f, 0.f, 0.f, 0.f, 0.f, 0.f, 0.f};
    int e0 = (qa == 0) ? rp[node] : rpm[3 * node + qa - 1];
    int e1 = (qb == 4) ? rp[node + 1] : rpm[3 * node + qb - 1];
    const unsigned short* xb = X + 8 * sl;
    int e = e0 + sub;
    for (; e + 3 * SUBS < e1; e += 4 * SUBS) {    // 4 independent gathers in flight
        int s0 = csr[e], s1 = csr[e + SUBS], s2 = csr[e + 2 * SUBS], s3 = csr[e + 3 * SUBS];
        uint4 u0 = *(const uint4*)(xb + (size_t)s0 * ldx);
        uint4 u1 = *(const uint4*)(xb + (size_t)s1 * ldx);
        uint4 u2 = *(const uint4*)(xb + (size_t)s2 * ldx);
        uint4 u3 = *(const uint4*)(xb + (size_t)s3 * ldx);
        acc8(a, u0); acc8(a, u1); acc8(a, u2); acc8(a, u3);
    }
    for (; e < e1; e += SUBS) {
        uint4 u = *(const uint4*)(xb + (size_t)csr[e] * ldx);
        acc8(a, u);
    }
    #pragma unroll
    for (int m = LPF; m < SUBS * LPF; m <<= 1)
        #pragma unroll
        for (int i = 0; i < 8; i++) a[i] += __shfl_xor(a[i], m, 64);
    if (sub == 0) {
        if (pin) {                           // carry partial from previous phase
            const float* pi = pin + (size_t)node * (LPF * 8) + 8 * sl;
            f32x4v p0 = __builtin_nontemporal_load((const f32x4v*)pi);
            f32x4v p1 = __builtin_nontemporal_load((const f32x4v*)(pi + 4));
            a[0] += p0[0]; a[1] += p0[1]; a[2] += p0[2]; a[3] += p0[3];
            a[4] += p1[0]; a[5] += p1[1]; a[6] += p1[2]; a[7] += p1[3];
        }
        if (pout) {                          // not final: store fp32 partial
            float* po = pout + (size_t)node * (LPF * 8) + 8 * sl;
            f32x4v v0 = {a[0], a[1], a[2], a[3]};
            f32x4v v1 = {a[4], a[5], a[6], a[7]};
            __builtin_nontemporal_store(v0, (f32x4v*)po);
            __builtin_nontemporal_store(v1, (f32x4v*)(po + 4));
        } else {                             // final phase: root/bias/relu/bf16
            if (root) {
                uint4 u = *(const uint4*)(root + (size_t)node * ldr + 8 * sl);
                acc8(a, u);
            }
            if (bias) {
                float4 b0 = *(const float4*)(bias + 8 * sl);
                float4 b1 = *(const float4*)(bias + 8 * sl + 4);
                a[0] += b0.x; a[1] += b0.y; a[2] += b0.z; a[3] += b0.w;
                a[4] += b1.x; a[5] += b1.y; a[6] += b1.z; a[7] += b1.w;
            }
            if (relu) {
                #pragma unroll
                for (int i = 0; i < 8; i++) a[i] = fmaxf(a[i], 0.f);
            }
            uint4 o;
            o.x = (unsigned)f2bf(a[0]) | ((unsigned)f2bf(a[1]) << 16);
            o.y = (unsigned)f2bf(a[2]) | ((unsigned)f2bf(a[3]) << 16);
            o.z = (unsigned)f2bf(a[4]) | ((unsigned)f2bf(a[5]) << 16);
            o.w = (unsigned)f2bf(a[6]) | ((unsigned)f2bf(a[7]) << 16);
            *(uint4*)(OUT + (size_t)node * ldo + 8 * sl) = o;
        }
    }
}

// ---------------- pool + head (R17 shape) ------------------------------------

__global__ void aggpool_kernel(const float* __restrict__ s, const float* __restrict__ t,
                               const int* __restrict__ rp, const int* __restrict__ csr,
                               const int* __restrict__ batch, float* __restrict__ gsum,
                               int* __restrict__ cnt, int N) {
    __shared__ float ls[NGRAPH];
    __shared__ int lc[NGRAPH];
    int tid = threadIdx.x;
    if (tid < NGRAPH) { ls[tid] = 0.f; lc[tid] = 0; }
    __syncthreads();
    int n = blockIdx.x * blockDim.x + tid;
    if (n < N) {
        float a = 0.f;
        int e = rp[n], e1 = rp[n + 1];
        for (; e + 3 < e1; e += 4) {
            int s0 = csr[e], s1 = csr[e + 1], s2 = csr[e + 2], s3 = csr[e + 3];
            a += s[s0] + s[s1] + s[s2] + s[s3];
        }
        for (; e < e1; e++) a += s[csr[e]];
        int g = batch[n];
        atomicAdd(&ls[g], a + t[n]);
        atomicAdd(&lc[g], 1);
    }
    __syncthreads();
    if (tid < NGRAPH && lc[tid] > 0) {
        atomicAdd(&gsum[tid], ls[tid]);
        atomicAdd(&cnt[tid], lc[tid]);
    }
}

__global__ void final_kernel(const float* __restrict__ gsum, const int* __restrict__ cnt,
                             const float* __restrict__ cbuf, const float* __restrict__ head_b,
                             float* __restrict__ out) {
    int g = threadIdx.x;
    if (g < NGRAPH) {
        float c = (float)(cnt[g] > 0 ? cnt[g] : 1);
        out[g] = gsum[g] / c + cbuf[0] + head_b[0];
    }
}

// ---------------- launch ----------------

extern "C" void kernel_launch(void* const* d_in, const int* in_sizes, int n_in,
                              void* d_out, int out_size, void* d_ws, size_t ws_size,
                              hipStream_t stream) {
    const float* x       = (const float*)d_in[0];
    const int*   edge    = (const int*)d_in[1];
    const int*   batch   = (const int*)d_in[2];
    const float* w1_rel  = (const float*)d_in[3];
    const float* w1_root = (const float*)d_in[4];
    const float* b1      = (const float*)d_in[5];
    const float* w2_rel  = (const float*)d_in[6];
    const float* w2_root = (const float*)d_in[7];
    const float* b2      = (const float*)d_in[8];
    const float* w3_rel  = (const float*)d_in[9];
    const float* w3_root = (const float*)d_in[10];
    const float* b3      = (const float*)d_in[11];
    const float* w4_rel  = (const float*)d_in[12];
    const float* w4_root = (const float*)d_in[13];
    const float* b4      = (const float*)d_in[14];
    const float* head_w  = (const float*)d_in[15];
    const float* head_b  = (const float*)d_in[16];
    float* out = (float*)d_out;

    const int N = NNODES, E = NEDGES;
    const int* esrc = edge;
    const int* edst = edge + E;

    char* ws = (char*)d_ws;
    size_t off = 0;
    auto alloc = [&](size_t bytes) -> char* {
        char* p = ws + off;
        off = (off + bytes + 255) & ~(size_t)255;
        return p;
    };
    // zeroed region first (one fused zeroing pass): gsum, cnt, sbuf, tbuf
    float* gsum  = (float*)alloc(NGRAPH * 4);
    int*   cnt   = (int*)alloc(NGRAPH * 4);
    float* sbuf  = (float*)alloc((size_t)N * 4);
    float* tbuf  = (float*)alloc((size_t)N * 4);
    size_t zero_bytes = off;                               // 256-aligned, /16 ok
    int*   bcnt  = (int*)alloc((size_t)NBUK * NBUK * 4);   // bucket x block counts
    int*   bsum  = (int*)alloc(256 * 4);                   // RAW bucket totals
    int*   sbsum = (int*)alloc(256 * 4);                   // scanned bucket offsets
    int*   rp    = (int*)alloc((size_t)(N + 1) * 4);
    int*   rpm   = (int*)alloc((size_t)N * 3 * 4);         // quartile boundaries
    int*   csr   = (int*)alloc((size_t)E * 4);
    unsigned long long* pedge = (unsigned long long*)alloc((size_t)E * 8);
    unsigned short* xbf    = (unsigned short*)alloc((size_t)N * 128 * 2);
    unsigned short* z1     = (unsigned short*)alloc((size_t)N * 128 * 2);  // [x@w1_rel | x@w1_root]
    unsigned short* combo2 = (unsigned short*)alloc((size_t)N * 128 * 2);  // [agg2 | h1]
    unsigned short* combo3 = (unsigned short*)alloc((size_t)N * 256 * 2);  // [agg3 | h2]
    unsigned short* pL1    = (unsigned short*)alloc(4 * 8 * 512 * 2);      // also DMA overrun slack
    unsigned short* pL2    = (unsigned short*)alloc(4 * 8 * 512 * 2);
    unsigned short* pL3    = (unsigned short*)alloc(6 * 16 * 512 * 2);
    float* wr    = (float*)alloc(192 * 4);
    float* wt    = (float*)alloc(192 * 4);
    float* cbuf  = (float*)alloc(4);
    (void)ws_size;

    // fp32 partial buffers overlay memory that is dead during the agg phases:
    // pbufA (12.8MB, agg1/agg2) = xbf (dead after gemm1);
    // pbufB (25.6MB, agg3)      = xbf+z1 (both dead after agg1 final phase).
    float* pbufA = (float*)xbf;
    float* pbufB = (float*)xbf;

    const int TB = 256;

    // CSR build + prep; gemm1 overlapped with partition/build (disjoint ranges)
    histprep_kernel<<<NBUK + PREP_NB, 256, 0, stream>>>(
        edst, bcnt, x, xbf, w1_rel, w1_root, w2_rel, w2_root, w3_rel, w3_root,
        pL1, pL2, pL3, w4_rel, w4_root, b4, head_w, wr, wt, cbuf);
    scanzero_kernel<<<NBUK + ZNB, 256, 0, stream>>>(
        bcnt, bsum, NBUK * NBUK, (float4*)ws, (int)(zero_bytes / 16));
    partgemm_kernel<<<NBUK + GB_SPLIT, 256, 0, stream>>>(
        esrc, edst, bcnt, bsum, sbsum, pedge, xbf, pL1, z1, N);
    buildgemm_kernel<<<NBUK + (RCHUNK * 8 - GB_SPLIT), 256, 0, stream>>>(
        pedge, sbsum, rp, rpm, csr, xbf, pL1, z1, N);

    // agg1: h1 = relu(nbrsum(z1[:,:64]) + z1[:,64:] + b1) -> combo2[:,64:]
    agg_kernel_v7<8, 2><<<(N * 16 + TB - 1) / TB, TB, 0, stream>>>(
        z1, 128, rp, rpm, csr, 0, 2, nullptr, pbufA,
        nullptr, 0, nullptr, 0, nullptr, 0, N);
    agg_kernel_v7<8, 2><<<(N * 16 + TB - 1) / TB, TB, 0, stream>>>(
        z1, 128, rp, rpm, csr, 2, 4, pbufA, nullptr,
        z1 + 64, 128, b1, 1, combo2 + 64, 128, N);
    // agg2 = nbrsum(h1) -> combo2[:,:64]
    agg_kernel_v7<8, 2><<<(N * 16 + TB - 1) / TB, TB, 0, stream>>>(
        combo2 + 64, 128, rp, rpm, csr, 0, 2, nullptr, pbufA,
        nullptr, 0, nullptr, 0, nullptr, 0, N);
    agg_kernel_v7<8, 2><<<(N * 16 + TB - 1) / TB, TB, 0, stream>>>(
        combo2 + 64, 128, rp, rpm, csr, 2, 4, pbufA, nullptr,
        nullptr, 0, nullptr, 0, combo2, 128, N);
    // L2: h2 = relu(combo2 @ [w2_rel; w2_root] + b2) -> combo3[:,128:]
    gemm_v5<8, 4, 1, 0, 8><<<RCHUNK * 8, 256, 0, stream>>>(
        combo2, pL2, b2, combo3, 256, 128, 1, N, nullptr, nullptr, nullptr, nullptr);
    // agg3 = nbrsum(h2) -> combo3[:,:128]  (4 quartile phases)
    agg_kernel_v7<16, 2><<<(N * 32 + TB - 1) / TB, TB, 0, stream>>>(
        combo3 + 128, 256, rp, rpm, csr, 0, 1, nullptr, pbufB,
        nullptr, 0, nullptr, 0, nullptr, 0, N);
    agg_kernel_v7<16, 2><<<(N * 32 + TB - 1) / TB, TB, 0, stream>>>(
        combo3 + 128, 256, rp, rpm, csr, 1, 2, pbufB, pbufB,
        nullptr, 0, nullptr, 0, nullptr, 0, N);
    agg_kernel_v7<16, 2><<<(N * 32 + TB - 1) / TB, TB, 0, stream>>>(
        combo3 + 128, 256, rp, rpm, csr, 2, 3, pbufB, pbufB,
        nullptr, 0, nullptr, 0, nullptr, 0, N);
    agg_kernel_v7<16, 2><<<(N * 32 + TB - 1) / TB, TB, 0, stream>>>(
        combo3 + 128, 256, rp, rpm, csr, 3, 4, pbufB, nullptr,
        nullptr, 0, nullptr, 0, combo3, 256, N);
    // L3 + fused L4 projection (K=256, col-halved, A chunked 16KB, LDS 64KB)
    gemm_v5<16, 3, 2, 1, 4><<<RCHUNK * 8 * 2, 256, 0, stream>>>(
        combo3, pL3, b3, nullptr, 0, 0, 0, N, wr, wt, sbuf, tbuf);

    // pool + head
    aggpool_kernel<<<(N + TB - 1) / TB, TB, 0, stream>>>(sbuf, tbuf, rp, csr, batch, gsum, cnt, N);
    final_kernel<<<1, 64, 0, stream>>>(gsum, cnt, cbuf, head_b, out);
}

// Round 8
// 281.535 us; speedup vs baseline: 1.1329x; 1.0764x over previous
//
#include <hip/hip_runtime.h>

// GraphConv GNN forward, MI355X — Round 23.
// Ledger: R18 waves(+8), R19 concurrent slices(+23), R20 ILP(+10), R21 sort
// (+78, agg unchanged), R22 launch-phases(+62, CONFOUNDED: 205MB partial
// streams flushed the L2 residency being tested). The clean capacity test is
// COLUMN-split across launches: no partials (each launch owns its output
// cols), launches serialize, per-launch gather working set = 50000 x 64B
// = 3.2MB < 4MB L2, per-edge transaction count UNCHANGED.
//  - agg1/agg2: 2 launches each (32-short col chunks)
//  - agg3: 4 launches
//  - all else exact R17 (241.2us config)
// Read: ~195-220 => L2-hit gathers are faster, capacity was the issue;
// ~245-250 => transaction cost independent of hit level => gather floor real.

#define NNODES 50000
#define NEDGES 800000
#define NGRAPH 64
#define NBUK 256                          // dst buckets
#define BSZ 196                           // nodes per bucket (196*256 >= 50000)
#define EPB (NEDGES / NBUK)               // 3125 edges per partition block
#define CVT_NB (NNODES * 128 / 4 / 256)   // 6250
#define PACK_NB (160 * 512 / 256)         // 320
#define PREP_NB (CVT_NB + PACK_NB + 1)    // 6571
#define RGRID ((NNODES + 127) / 128)      // 391 row blocks
#define RCHUNK ((RGRID + 7) / 8)          // 49 chunks of 8 row blocks
#define GB_SPLIT 196                      // gemm1 row blocks in partition launch
#define ZNB 32                            // zeroing blocks riding scan1 launch

typedef __attribute__((ext_vector_type(8))) __bf16 bf16x8;
typedef __attribute__((ext_vector_type(16))) float f32x16;

__device__ __forceinline__ unsigned short f2bf(float f) {
    unsigned u = __float_as_uint(f);
    u += 0x7fff + ((u >> 16) & 1);   // RNE
    return (unsigned short)(u >> 16);
}
__device__ __forceinline__ float bf2f(unsigned b) {
    return __uint_as_float(b << 16);
}

// async 16B global->LDS DMA; LDS dest is wave-uniform base + lane*16 [m104]
__device__ __forceinline__ void dma16(const void* g, void* l) {
    __builtin_amdgcn_global_load_lds(
        (const __attribute__((address_space(1))) void*)g,
        (__attribute__((address_space(3))) void*)l, 16, 0, 0);
}

// ---------------- prep body (cvt / weight pack / head fold) ------------------

__device__ __forceinline__ void pack32(const float* __restrict__ W, unsigned short* __restrict__ dst,
                                       int KS_tot, int ks0, int dcols, int ct0,
                                       int tl, int ksl, int lane, int j) {
    int k = ksl * 16 + ((lane >> 5) << 3) + j;
    int col = tl * 32 + (lane & 31);
    dst[(((size_t)(ct0 + tl) * KS_tot + (ks0 + ksl)) * 64 + lane) * 8 + j] = f2bf(W[k * dcols + col]);
}

__device__ void prep_body(int b, int tid,
                          const float* x, unsigned short* xbf,
                          const float* w1_rel, const float* w1_root,
                          const float* w2_rel, const float* w2_root,
                          const float* w3_rel, const float* w3_root,
                          unsigned short* pL1, unsigned short* pL2, unsigned short* pL3,
                          const float* w4_rel, const float* w4_root,
                          const float* b4, const float* head_w,
                          float* wr, float* wt, float* cbuf) {
    if (b < CVT_NB) {                       // fp32 -> bf16 of x
        int i = b * 256 + tid;
        float4 v = ((const float4*)x)[i];
        unsigned lo = (unsigned)f2bf(v.x) | ((unsigned)f2bf(v.y) << 16);
        unsigned hi = (unsigned)f2bf(v.z) | ((unsigned)f2bf(v.w) << 16);
        ((uint2*)xbf)[i] = make_uint2(lo, hi);
    } else if (b < CVT_NB + PACK_NB) {      // weight packing (32x32x16 B-frag order)
        int idx = (b - CVT_NB) * 256 + tid;
        int g = idx >> 9;
        int t = idx & 511;
        int lane = (t >> 3) & 63, j = t & 7;
        if (g < 16)       { int gl = g;       pack32(w1_rel,  pL1, 8,  0, 64,  0, gl / 8, gl % 8, lane, j); }
        else if (g < 32)  { int gl = g - 16;  pack32(w1_root, pL1, 8,  0, 64,  2, gl / 8, gl % 8, lane, j); }
        else if (g < 48)  { int gl = g - 32;  pack32(w2_rel,  pL2, 8,  0, 128, 0, gl / 4, gl % 4, lane, j); }
        else if (g < 64)  { int gl = g - 48;  pack32(w2_root, pL2, 8,  4, 128, 0, gl / 4, gl % 4, lane, j); }
        else if (g < 112) { int gl = g - 64;  pack32(w3_rel,  pL3, 16, 0, 192, 0, gl / 8, gl % 8, lane, j); }
        else              { int gl = g - 112; pack32(w3_root, pL3, 16, 8, 192, 0, gl / 8, gl % 8, lane, j); }
    } else {                                // head folding
        if (tid < 192) {
            float ar = 0.f, at = 0.f;
            for (int j = 0; j < 64; j++) {
                float hw = head_w[j];
                ar = fmaf(w4_rel[tid * 64 + j], hw, ar);
                at = fmaf(w4_root[tid * 64 + j], hw, at);
            }
            wr[tid] = ar;
            wt[tid] = at;
        } else if (tid == 192) {
            float c = 0.f;
            for (int j = 0; j < 64; j++) c = fmaf(b4[j], head_w[j], c);
            cbuf[0] = c;
        }
    }
}

// ---------------- fused hist + prep: disjoint block ranges, no fences --------

__global__ void __launch_bounds__(256) histprep_kernel(
    const int* __restrict__ edst, int* __restrict__ bcnt,
    const float* __restrict__ x, unsigned short* __restrict__ xbf,
    const float* __restrict__ w1_rel, const float* __restrict__ w1_root,
    const float* __restrict__ w2_rel, const float* __restrict__ w2_root,
    const float* __restrict__ w3_rel, const float* __restrict__ w3_root,
    unsigned short* __restrict__ pL1, unsigned short* __restrict__ pL2,
    unsigned short* __restrict__ pL3,
    const float* __restrict__ w4_rel, const float* __restrict__ w4_root,
    const float* __restrict__ b4, const float* __restrict__ head_w,
    float* __restrict__ wr, float* __restrict__ wt, float* __restrict__ cbuf)
{
    int tid = threadIdx.x, b = blockIdx.x;
    if (b < NBUK) {                          // histogram of edge chunk b
        __shared__ int h[NBUK];
        h[tid] = 0;
        __syncthreads();
        int end = (b + 1) * EPB;
        for (int i = b * EPB + tid; i < end; i += 256)
            atomicAdd(&h[edst[i] / BSZ], 1);
        __syncthreads();
        bcnt[tid * NBUK + b] = h[tid];
    } else {                                 // prep work, concurrent
        prep_body(b - NBUK, tid, x, xbf, w1_rel, w1_root, w2_rel, w2_root,
                  w3_rel, w3_root, pL1, pL2, pL3, w4_rel, w4_root, b4, head_w,
                  wr, wt, cbuf);
    }
}

// ---------------- scan1 + workspace zeroing (fused, independent ranges) ------

__global__ void scanzero_kernel(int* __restrict__ a, int* __restrict__ bsum, int n,
                                float4* __restrict__ zb, int zn16) {
    __shared__ int buf[256];
    int tid = threadIdx.x, b = blockIdx.x;
    if (b < NBUK) {                          // per-row local exclusive scan
        int i = b * 256 + tid;
        int v = (i < n) ? a[i] : 0;
        buf[tid] = v;
        __syncthreads();
        #pragma unroll
        for (int off = 1; off < 256; off <<= 1) {
            int t = (tid >= off) ? buf[tid - off] : 0;
            __syncthreads();
            buf[tid] += t;
            __syncthreads();
        }
        if (i < n) a[i] = buf[tid] - v;      // local exclusive (in-place)
        if (tid == 255) bsum[b] = buf[255];  // RAW row total (scan moved to consumers)
    } else {                                 // zero gsum/cnt/sbuf/tbuf region
        float4 zero = make_float4(0.f, 0.f, 0.f, 0.f);
        for (int i = (b - NBUK) * 256 + tid; i < zn16; i += ZNB * 256) zb[i] = zero;
    }
}

// ---------------- MFMA GEMM v5 body (LDS passed in by caller) ----------------

template<int KS, int NT, int NHALF, int ST, int KCH>
__device__ void gemm_body(
    unsigned short* sB, unsigned short* sA, int i,
    const unsigned short* __restrict__ A, const unsigned short* __restrict__ Wall,
    const float* __restrict__ bias, unsigned short* __restrict__ OUT,
    int ldo, int ocol0, int relu, int N,
    const float* __restrict__ wrp, const float* __restrict__ wtp,
    float* __restrict__ sb, float* __restrict__ tb)
{
    const int K = KS * 16;                  // elements (shorts) per row
    const int CPC = KCH * 2;                // 16B chunks per row per A-chunk

    int chunk = i / (8 * NHALF);
    int rem = i - chunk * (8 * NHALF);
    int halfsel = rem >> 3;
    int rowb = chunk * 8 + (rem & 7);       // halves of a rowb share blockIdx%8
    int rbase = rowb * 128;
    if (rbase >= N) return;                 // uniform per block

    int tid = threadIdx.x;
    int wave = tid >> 6, lane = tid & 63;
    int l32 = lane & 31, half = lane >> 5;
    const unsigned short* W = Wall + (size_t)halfsel * NT * KS * 512;

    // stage B once (linear)
    #pragma unroll
    for (int j = 0; j < NT * KS * 64 / 256; j++) {
        int p = j * 256 + wave * 64;        // wave-uniform base unit
        dma16(W + ((size_t)p + lane) * 8, sB + (size_t)p * 8);
    }

    f32x16 acc[NT];
    #pragma unroll
    for (int t = 0; t < NT; t++)
        #pragma unroll
        for (int r = 0; r < 16; r++) acc[t][r] = 0.f;

    int lr = wave * 32 + l32;               // local row of this lane's A frags

    for (int kb = 0; kb < KS; kb += KCH) {
        if (kb > 0) __syncthreads();        // protect sA overwrite
        // stage A chunk: 128 rows x KCH ks, XOR-swizzled 16B chunks
        #pragma unroll
        for (int j = 0; j < 128 * CPC / 256; j++) {
            int p = j * 256 + wave * 64 + lane;
            int r = p / CPC;
            int c = p - r * CPC;
            int cg = c ^ (r & (CPC - 1));
            dma16(A + (size_t)(rbase + r) * K + kb * 16 + cg * 8,
                  sA + (size_t)(j * 256 + wave * 64) * 8);
        }
        __syncthreads();                    // drains vmcnt before barrier
        #pragma unroll
        for (int l = 0; l < KCH; l++) {
            int cs = (l * 2 + half) ^ (lr & (CPC - 1));
            bf16x8 a = *(const bf16x8*)(sA + (size_t)lr * (KCH * 16) + cs * 8);
            int ks = kb + l;
            #pragma unroll
            for (int t = 0; t < NT; t++) {
                bf16x8 b = *(const bf16x8*)(sB + ((size_t)(t * KS + ks) * 64 + lane) * 8);
                acc[t] = __builtin_amdgcn_mfma_f32_32x32x16_bf16(a, b, acc[t], 0, 0, 0);
            }
        }
    }

    int wrbase = rbase + wave * 32;
    if constexpr (ST) {
        // fused L4 projection: partial s/t per row via shfl reduce + atomicAdd
        #pragma unroll
        for (int reg = 0; reg < 16; reg++) {
            int row = wrbase + (reg & 3) + 8 * (reg >> 2) + 4 * half;
            float sv = 0.f, tv = 0.f;
            #pragma unroll
            for (int t = 0; t < NT; t++) {
                int col = halfsel * NT * 32 + t * 32 + l32;
                float v = fmaxf(acc[t][reg] + bias[col], 0.f);
                sv = fmaf(v, wrp[col], sv);
                tv = fmaf(v, wtp[col], tv);
            }
            #pragma unroll
            for (int m = 1; m < 32; m <<= 1) {
                sv += __shfl_xor(sv, m, 64);
                tv += __shfl_xor(tv, m, 64);
            }
            if (l32 == 0 && row < N) {
                atomicAdd(&sb[row], sv);
                atomicAdd(&tb[row], tv);
            }
        }
    } else {
        #pragma unroll
        for (int t = 0; t < NT; t++) {
            int col = t * 32 + l32;
            float bi = bias ? bias[col] : 0.f;
            #pragma unroll
            for (int reg = 0; reg < 16; reg++) {
                int row = wrbase + (reg & 3) + 8 * (reg >> 2) + 4 * half;
                if (row < N) {
                    float v = acc[t][reg] + bi;
                    if (relu) v = fmaxf(v, 0.f);
                    OUT[(size_t)row * ldo + ocol0 + col] = f2bf(v);
                }
            }
        }
    }
}

// standalone GEMM kernel (L2, L3+L4)
template<int KS, int NT, int NHALF, int ST, int KCH>
__global__ __launch_bounds__(256) void gemm_v5(
    const unsigned short* __restrict__ A, const unsigned short* __restrict__ Wall,
    const float* __restrict__ bias, unsigned short* __restrict__ OUT,
    int ldo, int ocol0, int relu, int N,
    const float* __restrict__ wrp, const float* __restrict__ wtp,
    float* __restrict__ sb, float* __restrict__ tb)
{
    __shared__ __align__(16) unsigned short sB[NT * KS * 512];
    __shared__ __align__(16) unsigned short sA[128 * KCH * 16];
    gemm_body<KS, NT, NHALF, ST, KCH>(sB, sA, blockIdx.x, A, Wall, bias, OUT,
                                      ldo, ocol0, relu, N, wrp, wtp, sb, tb);
}

// ---------------- partition + gemm1(first half), fused block ranges ----------
// partition block: exclusive-scans raw bucket totals in LDS (replaces scan2);
// block 0 stores the scanned offsets for build. LDS overlaid with gemm's 64KB.

__global__ void __launch_bounds__(256) partgemm_kernel(
    const int* __restrict__ src, const int* __restrict__ dst,
    const int* __restrict__ cnt, const int* __restrict__ braw,
    int* __restrict__ sbsum, unsigned long long* __restrict__ pedge,
    const unsigned short* __restrict__ A, const unsigned short* __restrict__ W,
    unsigned short* __restrict__ OUT, int N)
{
    __shared__ __align__(16) unsigned short smem[32768];   // 64KB, overlaid
    int tid = threadIdx.x, b = blockIdx.x;
    if (b < NBUK) {
        int* lbase = (int*)smem;             // 256 ints
        int* sscan = lbase + 256;            // 256 ints
        int v = braw[tid];
        sscan[tid] = v;
        __syncthreads();
        #pragma unroll
        for (int off = 1; off < 256; off <<= 1) {
            int t = (tid >= off) ? sscan[tid - off] : 0;
            __syncthreads();
            sscan[tid] += t;
            __syncthreads();
        }
        int ex = sscan[tid] - v;             // exclusive bucket offset
        if (b == 0) sbsum[tid] = ex;         // for build_kernel
        lbase[tid] = cnt[tid * NBUK + b] + ex;
        __syncthreads();
        int end = (b + 1) * EPB;
        for (int i = b * EPB + tid; i < end; i += 256) {
            int s = src[i], d = dst[i];
            int pos = atomicAdd(&lbase[d / BSZ], 1);
            pedge[pos] = (unsigned long long)(unsigned)s | ((unsigned long long)(unsigned)d << 32);
        }
    } else {
        gemm_body<8, 4, 1, 0, 8>(smem, smem + 16384, b - NBUK,
                                 A, W, nullptr, OUT, 128, 0, 0, N,
                                 nullptr, nullptr, nullptr, nullptr);
    }
}

// ---------------- build + gemm1(second half), fused block ranges -------------

__global__ void __launch_bounds__(256) buildgemm_kernel(
    const unsigned long long* __restrict__ pedge, const int* __restrict__ sbsum,
    int* __restrict__ rp, int* __restrict__ csr,
    const unsigned short* __restrict__ A, const unsigned short* __restrict__ W,
    unsigned short* __restrict__ OUT, int N)
{
    __shared__ __align__(16) unsigned short smem[32768];   // 64KB, overlaid
    int tid = threadIdx.x, b = blockIdx.x;
    if (b < NBUK) {
        int* sdeg  = (int*)smem;
        int* sc    = sdeg + 256;
        int* sbase = sc + 256;
        int* sfill = sbase + 256;
        int node0 = b * BSZ;
        int ncnt = NNODES - node0;
        if (ncnt > BSZ) ncnt = BSZ;
        if (ncnt < 0) ncnt = 0;
        int seg0 = sbsum[b];
        int seg1 = (b + 1 < NBUK) ? sbsum[b + 1] : NEDGES;
        sdeg[tid] = 0;
        sfill[tid] = 0;
        __syncthreads();
        for (int i = seg0 + tid; i < seg1; i += 256)
            atomicAdd(&sdeg[(int)(pedge[i] >> 32) - node0], 1);
        __syncthreads();
        sc[tid] = sdeg[tid];
        __syncthreads();
        #pragma unroll
        for (int off = 1; off < 256; off <<= 1) {
            int t = (tid >= off) ? sc[tid - off] : 0;
            __syncthreads();
            sc[tid] += t;
            __syncthreads();
        }
        sbase[tid] = sc[tid] - sdeg[tid];    // exclusive within bucket
        if (tid < ncnt) rp[node0 + tid] = seg0 + sbase[tid];
        if (b == NBUK - 1 && tid == 0) rp[NNODES] = NEDGES;
        __syncthreads();
        for (int i = seg0 + tid; i < seg1; i += 256) {
            unsigned long long p = pedge[i];
            int d = (int)(p >> 32) - node0;
            int pos = atomicAdd(&sfill[d], 1);
            csr[seg0 + sbase[d] + pos] = (int)(p & 0xffffffffu);
        }
    } else {
        gemm_body<8, 4, 1, 0, 8>(smem, smem + 16384, GB_SPLIT + (b - NBUK),
                                 A, W, nullptr, OUT, 128, 0, 0, N,
                                 nullptr, nullptr, nullptr, nullptr);
    }
}

// ---------------- bf16 neighbor-sum via CSR gather, column chunk per launch --
// co = column offset in shorts; gather working set per launch = N x 64B lines
// (3.2MB, L2-resident). Launch-level serialization; no partials needed.

__device__ __forceinline__ void acc8(float* a, uint4 u) {
    a[0] += bf2f(u.x & 0xffffu); a[1] += bf2f(u.x >> 16);
    a[2] += bf2f(u.y & 0xffffu); a[3] += bf2f(u.y >> 16);
    a[4] += bf2f(u.z & 0xffffu); a[5] += bf2f(u.z >> 16);
    a[6] += bf2f(u.w & 0xffffu); a[7] += bf2f(u.w >> 16);
}

template<int LPF, int SUBS>
__global__ void agg_kernel_v8(const unsigned short* __restrict__ X, int ldx,
                              const int* __restrict__ rp, const int* __restrict__ csr,
                              int co,
                              const unsigned short* __restrict__ root, int ldr,
                              const float* __restrict__ bias, int relu,
                              unsigned short* __restrict__ OUT, int ldo, int N) {
    int t = blockIdx.x * blockDim.x + threadIdx.x;
    int node = t / (SUBS * LPF);
    int r = t % (SUBS * LPF);
    int sub = r / LPF;
    int sl = r % LPF;
    if (node >= N) return;
    float a[8] = {0.f, 0.f, 0.f, 0.f, 0.f, 0.f, 0.f, 0.f};
    int e0 = rp[node], e1 = rp[node + 1];
    const unsigned short* xb = X + co + 8 * sl;
    int e = e0 + sub;
    for (; e + 3 * SUBS < e1; e += 4 * SUBS) {    // 4 independent gathers in flight
        int s0 = csr[e], s1 = csr[e + SUBS], s2 = csr[e + 2 * SUBS], s3 = csr[e + 3 * SUBS];
        uint4 u0 = *(const uint4*)(xb + (size_t)s0 * ldx);
        uint4 u1 = *(const uint4*)(xb + (size_t)s1 * ldx);
        uint4 u2 = *(const uint4*)(xb + (size_t)s2 * ldx);
        uint4 u3 = *(const uint4*)(xb + (size_t)s3 * ldx);
        acc8(a, u0); acc8(a, u1); acc8(a, u2); acc8(a, u3);
    }
    for (; e < e1; e += SUBS) {
        uint4 u = *(const uint4*)(xb + (size_t)csr[e] * ldx);
        acc8(a, u);
    }
    #pragma unroll
    for (int m = LPF; m < SUBS * LPF; m <<= 1)
        #pragma unroll
        for (int i = 0; i < 8; i++) a[i] += __shfl_xor(a[i], m, 64);
    if (sub == 0) {
        if (root) {
            uint4 u = *(const uint4*)(root + (size_t)node * ldr + co + 8 * sl);
            acc8(a, u);
        }
        if (bias) {
            float4 b0 = *(const float4*)(bias + co + 8 * sl);
            float4 b1 = *(const float4*)(bias + co + 8 * sl + 4);
            a[0] += b0.x; a[1] += b0.y; a[2] += b0.z; a[3] += b0.w;
            a[4] += b1.x; a[5] += b1.y; a[6] += b1.z; a[7] += b1.w;
        }
        if (relu) {
            #pragma unroll
            for (int i = 0; i < 8; i++) a[i] = fmaxf(a[i], 0.f);
        }
        uint4 o;
        o.x = (unsigned)f2bf(a[0]) | ((unsigned)f2bf(a[1]) << 16);
        o.y = (unsigned)f2bf(a[2]) | ((unsigned)f2bf(a[3]) << 16);
        o.z = (unsigned)f2bf(a[4]) | ((unsigned)f2bf(a[5]) << 16);
        o.w = (unsigned)f2bf(a[6]) | ((unsigned)f2bf(a[7]) << 16);
        *(uint4*)(OUT + (size_t)node * ldo + co + 8 * sl) = o;
    }
}

// ---------------- pool + head (R17 shape) ------------------------------------

__global__ void aggpool_kernel(const float* __restrict__ s, const float* __restrict__ t,
                               const int* __restrict__ rp, const int* __restrict__ csr,
                               const int* __restrict__ batch, float* __restrict__ gsum,
                               int* __restrict__ cnt, int N) {
    __shared__ float ls[NGRAPH];
    __shared__ int lc[NGRAPH];
    int tid = threadIdx.x;
    if (tid < NGRAPH) { ls[tid] = 0.f; lc[tid] = 0; }
    __syncthreads();
    int n = blockIdx.x * blockDim.x + tid;
    if (n < N) {
        float a = 0.f;
        int e = rp[n], e1 = rp[n + 1];
        for (; e + 3 < e1; e += 4) {
            int s0 = csr[e], s1 = csr[e + 1], s2 = csr[e + 2], s3 = csr[e + 3];
            a += s[s0] + s[s1] + s[s2] + s[s3];
        }
        for (; e < e1; e++) a += s[csr[e]];
        int g = batch[n];
        atomicAdd(&ls[g], a + t[n]);
        atomicAdd(&lc[g], 1);
    }
    __syncthreads();
    if (tid < NGRAPH && lc[tid] > 0) {
        atomicAdd(&gsum[tid], ls[tid]);
        atomicAdd(&cnt[tid], lc[tid]);
    }
}

__global__ void final_kernel(const float* __restrict__ gsum, const int* __restrict__ cnt,
                             const float* __restrict__ cbuf, const float* __restrict__ head_b,
                             float* __restrict__ out) {
    int g = threadIdx.x;
    if (g < NGRAPH) {
        float c = (float)(cnt[g] > 0 ? cnt[g] : 1);
        out[g] = gsum[g] / c + cbuf[0] + head_b[0];
    }
}

// ---------------- launch ----------------

extern "C" void kernel_launch(void* const* d_in, const int* in_sizes, int n_in,
                              void* d_out, int out_size, void* d_ws, size_t ws_size,
                              hipStream_t stream) {
    const float* x       = (const float*)d_in[0];
    const int*   edge    = (const int*)d_in[1];
    const int*   batch   = (const int*)d_in[2];
    const float* w1_rel  = (const float*)d_in[3];
    const float* w1_root = (const float*)d_in[4];
    const float* b1      = (const float*)d_in[5];
    const float* w2_rel  = (const float*)d_in[6];
    const float* w2_root = (const float*)d_in[7];
    const float* b2      = (const float*)d_in[8];
    const float* w3_rel  = (const float*)d_in[9];
    const float* w3_root = (const float*)d_in[10];
    const float* b3      = (const float*)d_in[11];
    const float* w4_rel  = (const float*)d_in[12];
    const float* w4_root = (const float*)d_in[13];
    const float* b4      = (const float*)d_in[14];
    const float* head_w  = (const float*)d_in[15];
    const float* head_b  = (const float*)d_in[16];
    float* out = (float*)d_out;

    const int N = NNODES, E = NEDGES;
    const int* esrc = edge;
    const int* edst = edge + E;

    char* ws = (char*)d_ws;
    size_t off = 0;
    auto alloc = [&](size_t bytes) -> char* {
        char* p = ws + off;
        off = (off + bytes + 255) & ~(size_t)255;
        return p;
    };
    // zeroed region first (one fused zeroing pass): gsum, cnt, sbuf, tbuf
    float* gsum  = (float*)alloc(NGRAPH * 4);
    int*   cnt   = (int*)alloc(NGRAPH * 4);
    float* sbuf  = (float*)alloc((size_t)N * 4);
    float* tbuf  = (float*)alloc((size_t)N * 4);
    size_t zero_bytes = off;                               // 256-aligned, /16 ok
    int*   bcnt  = (int*)alloc((size_t)NBUK * NBUK * 4);   // bucket x block counts
    int*   bsum  = (int*)alloc(256 * 4);                   // RAW bucket totals
    int*   sbsum = (int*)alloc(256 * 4);                   // scanned bucket offsets
    int*   rp    = (int*)alloc((size_t)(N + 1) * 4);
    int*   csr   = (int*)alloc((size_t)E * 4);
    unsigned long long* pedge = (unsigned long long*)alloc((size_t)E * 8);
    unsigned short* xbf    = (unsigned short*)alloc((size_t)N * 128 * 2);
    unsigned short* z1     = (unsigned short*)alloc((size_t)N * 128 * 2);  // [x@w1_rel | x@w1_root]
    unsigned short* combo2 = (unsigned short*)alloc((size_t)N * 128 * 2);  // [agg2 | h1]
    unsigned short* combo3 = (unsigned short*)alloc((size_t)N * 256 * 2);  // [agg3 | h2]
    unsigned short* pL1    = (unsigned short*)alloc(4 * 8 * 512 * 2);      // also DMA overrun slack
    unsigned short* pL2    = (unsigned short*)alloc(4 * 8 * 512 * 2);
    unsigned short* pL3    = (unsigned short*)alloc(6 * 16 * 512 * 2);
    float* wr    = (float*)alloc(192 * 4);
    float* wt    = (float*)alloc(192 * 4);
    float* cbuf  = (float*)alloc(4);
    (void)ws_size;

    const int TB = 256;
    const int AGG_NB = (N * 2 * 4 + TB - 1) / TB;   // blocks per col-chunk launch

    // CSR build + prep; gemm1 overlapped with partition/build (disjoint ranges)
    histprep_kernel<<<NBUK + PREP_NB, 256, 0, stream>>>(
        edst, bcnt, x, xbf, w1_rel, w1_root, w2_rel, w2_root, w3_rel, w3_root,
        pL1, pL2, pL3, w4_rel, w4_root, b4, head_w, wr, wt, cbuf);
    scanzero_kernel<<<NBUK + ZNB, 256, 0, stream>>>(
        bcnt, bsum, NBUK * NBUK, (float4*)ws, (int)(zero_bytes / 16));
    partgemm_kernel<<<NBUK + GB_SPLIT, 256, 0, stream>>>(
        esrc, edst, bcnt, bsum, sbsum, pedge, xbf, pL1, z1, N);
    buildgemm_kernel<<<NBUK + (RCHUNK * 8 - GB_SPLIT), 256, 0, stream>>>(
        pedge, sbsum, rp, csr, xbf, pL1, z1, N);

    // agg1: h1 = relu(nbrsum(z1[:,:64]) + z1[:,64:] + b1) -> combo2[:,64:]
    // 2 col-chunk launches, each gather table = 3.2MB (L2-resident)
    agg_kernel_v8<4, 2><<<AGG_NB, TB, 0, stream>>>(z1, 128, rp, csr, 0,
                                                   z1 + 64, 128, b1, 1, combo2 + 64, 128, N);
    agg_kernel_v8<4, 2><<<AGG_NB, TB, 0, stream>>>(z1, 128, rp, csr, 32,
                                                   z1 + 64, 128, b1, 1, combo2 + 64, 128, N);
    // agg2 = nbrsum(h1) -> combo2[:,:64]
    agg_kernel_v8<4, 2><<<AGG_NB, TB, 0, stream>>>(combo2 + 64, 128, rp, csr, 0,
                                                   nullptr, 0, nullptr, 0, combo2, 128, N);
    agg_kernel_v8<4, 2><<<AGG_NB, TB, 0, stream>>>(combo2 + 64, 128, rp, csr, 32,
                                                   nullptr, 0, nullptr, 0, combo2, 128, N);
    // L2: h2 = relu(combo2 @ [w2_rel; w2_root] + b2) -> combo3[:,128:]
    gemm_v5<8, 4, 1, 0, 8><<<RCHUNK * 8, 256, 0, stream>>>(
        combo2, pL2, b2, combo3, 256, 128, 1, N, nullptr, nullptr, nullptr, nullptr);
    // agg3 = nbrsum(h2) -> combo3[:,:128]  (4 col-chunk launches)
    agg_kernel_v8<4, 2><<<AGG_NB, TB, 0, stream>>>(combo3 + 128, 256, rp, csr, 0,
                                                   nullptr, 0, nullptr, 0, combo3, 256, N);
    agg_kernel_v8<4, 2><<<AGG_NB, TB, 0, stream>>>(combo3 + 128, 256, rp, csr, 32,
                                                   nullptr, 0, nullptr, 0, combo3, 256, N);
    agg_kernel_v8<4, 2><<<AGG_NB, TB, 0, stream>>>(combo3 + 128, 256, rp, csr, 64,
                                                   nullptr, 0, nullptr, 0, combo3, 256, N);
    agg_kernel_v8<4, 2><<<AGG_NB, TB, 0, stream>>>(combo3 + 128, 256, rp, csr, 96,
                                                   nullptr, 0, nullptr, 0, combo3, 256, N);
    // L3 + fused L4 projection (K=256, col-halved, A chunked 16KB, LDS 64KB)
    gemm_v5<16, 3, 2, 1, 4><<<RCHUNK * 8 * 2, 256, 0, stream>>>(
        combo3, pL3, b3, nullptr, 0, 0, 0, N, wr, wt, sbuf, tbuf);

    // pool + head
    aggpool_kernel<<<(N + TB - 1) / TB, TB, 0, stream>>>(sbuf, tbuf, rp, csr, batch, gsum, cnt, N);
    final_kernel<<<1, 64, 0, stream>>>(gsum, cnt, cbuf, head_b, out);
}

// Round 9
// 239.380 us; speedup vs baseline: 1.3324x; 1.1761x over previous
//
#include <hip/hip_runtime.h>

// GraphConv GNN forward, MI355X — Round 24.
// R18-R23 ledger: every agg restructure (waves/slices/ILP/sort/phases/colsplit)
// null or negative => aggs at HW rate AND smaller than assumed (never in top-5
// => each <=40us; all three ~90us). Pivot to GEMMs, never touched: gemm2 is
// 391 blocks @64KB LDS = 2/CU cap => 1.53 blocks/CU, 256+135 tail, staging
// latency exposed. R24 = R17 exact + ONE change: column-halve gemm1+gemm2
// (NHALF=2, NT=2): 48KB/block => 3/CU, grid 784 = 3.06/CU one full round.
// Required fix: ST=0 C-write now adds halfsel*NT*32 (prev only halfsel=0).
// Cost: A staged twice (+4MB ~ +1us). Numerics bit-identical.
// Read: ~230-237 => GEMM latency theory right; 240-243 => GEMMs were fine.

#define NNODES 50000
#define NEDGES 800000
#define NGRAPH 64
#define NBUK 256                          // dst buckets
#define BSZ 196                           // nodes per bucket (196*256 >= 50000)
#define EPB (NEDGES / NBUK)               // 3125 edges per partition block
#define CVT_NB (NNODES * 128 / 4 / 256)   // 6250
#define PACK_NB (160 * 512 / 256)         // 320
#define PREP_NB (CVT_NB + PACK_NB + 1)    // 6571
#define RGRID ((NNODES + 127) / 128)      // 391 row blocks
#define RCHUNK ((RGRID + 7) / 8)          // 49 chunks of 8 row blocks
#define GB_SPLIT 392                      // gemm1 half-blocks in partition launch (of 784)
#define ZNB 32                            // zeroing blocks riding scan1 launch

typedef __attribute__((ext_vector_type(8))) __bf16 bf16x8;
typedef __attribute__((ext_vector_type(16))) float f32x16;

__device__ __forceinline__ unsigned short f2bf(float f) {
    unsigned u = __float_as_uint(f);
    u += 0x7fff + ((u >> 16) & 1);   // RNE
    return (unsigned short)(u >> 16);
}
__device__ __forceinline__ float bf2f(unsigned b) {
    return __uint_as_float(b << 16);
}

// async 16B global->LDS DMA; LDS dest is wave-uniform base + lane*16 [m104]
__device__ __forceinline__ void dma16(const void* g, void* l) {
    __builtin_amdgcn_global_load_lds(
        (const __attribute__((address_space(1))) void*)g,
        (__attribute__((address_space(3))) void*)l, 16, 0, 0);
}

// ---------------- prep body (cvt / weight pack / head fold) ------------------

__device__ __forceinline__ void pack32(const float* __restrict__ W, unsigned short* __restrict__ dst,
                                       int KS_tot, int ks0, int dcols, int ct0,
                                       int tl, int ksl, int lane, int j) {
    int k = ksl * 16 + ((lane >> 5) << 3) + j;
    int col = tl * 32 + (lane & 31);
    dst[(((size_t)(ct0 + tl) * KS_tot + (ks0 + ksl)) * 64 + lane) * 8 + j] = f2bf(W[k * dcols + col]);
}

__device__ void prep_body(int b, int tid,
                          const float* x, unsigned short* xbf,
                          const float* w1_rel, const float* w1_root,
                          const float* w2_rel, const float* w2_root,
                          const float* w3_rel, const float* w3_root,
                          unsigned short* pL1, unsigned short* pL2, unsigned short* pL3,
                          const float* w4_rel, const float* w4_root,
                          const float* b4, const float* head_w,
                          float* wr, float* wt, float* cbuf) {
    if (b < CVT_NB) {                       // fp32 -> bf16 of x
        int i = b * 256 + tid;
        float4 v = ((const float4*)x)[i];
        unsigned lo = (unsigned)f2bf(v.x) | ((unsigned)f2bf(v.y) << 16);
        unsigned hi = (unsigned)f2bf(v.z) | ((unsigned)f2bf(v.w) << 16);
        ((uint2*)xbf)[i] = make_uint2(lo, hi);
    } else if (b < CVT_NB + PACK_NB) {      // weight packing (32x32x16 B-frag order)
        int idx = (b - CVT_NB) * 256 + tid;
        int g = idx >> 9;
        int t = idx & 511;
        int lane = (t >> 3) & 63, j = t & 7;
        if (g < 16)       { int gl = g;       pack32(w1_rel,  pL1, 8,  0, 64,  0, gl / 8, gl % 8, lane, j); }
        else if (g < 32)  { int gl = g - 16;  pack32(w1_root, pL1, 8,  0, 64,  2, gl / 8, gl % 8, lane, j); }
        else if (g < 48)  { int gl = g - 32;  pack32(w2_rel,  pL2, 8,  0, 128, 0, gl / 4, gl % 4, lane, j); }
        else if (g < 64)  { int gl = g - 48;  pack32(w2_root, pL2, 8,  4, 128, 0, gl / 4, gl % 4, lane, j); }
        else if (g < 112) { int gl = g - 64;  pack32(w3_rel,  pL3, 16, 0, 192, 0, gl / 8, gl % 8, lane, j); }
        else              { int gl = g - 112; pack32(w3_root, pL3, 16, 8, 192, 0, gl / 8, gl % 8, lane, j); }
    } else {                                // head folding
        if (tid < 192) {
            float ar = 0.f, at = 0.f;
            for (int j = 0; j < 64; j++) {
                float hw = head_w[j];
                ar = fmaf(w4_rel[tid * 64 + j], hw, ar);
                at = fmaf(w4_root[tid * 64 + j], hw, at);
            }
            wr[tid] = ar;
            wt[tid] = at;
        } else if (tid == 192) {
            float c = 0.f;
            for (int j = 0; j < 64; j++) c = fmaf(b4[j], head_w[j], c);
            cbuf[0] = c;
        }
    }
}

// ---------------- fused hist + prep: disjoint block ranges, no fences --------

__global__ void __launch_bounds__(256) histprep_kernel(
    const int* __restrict__ edst, int* __restrict__ bcnt,
    const float* __restrict__ x, unsigned short* __restrict__ xbf,
    const float* __restrict__ w1_rel, const float* __restrict__ w1_root,
    const float* __restrict__ w2_rel, const float* __restrict__ w2_root,
    const float* __restrict__ w3_rel, const float* __restrict__ w3_root,
    unsigned short* __restrict__ pL1, unsigned short* __restrict__ pL2,
    unsigned short* __restrict__ pL3,
    const float* __restrict__ w4_rel, const float* __restrict__ w4_root,
    const float* __restrict__ b4, const float* __restrict__ head_w,
    float* __restrict__ wr, float* __restrict__ wt, float* __restrict__ cbuf)
{
    int tid = threadIdx.x, b = blockIdx.x;
    if (b < NBUK) {                          // histogram of edge chunk b
        __shared__ int h[NBUK];
        h[tid] = 0;
        __syncthreads();
        int end = (b + 1) * EPB;
        for (int i = b * EPB + tid; i < end; i += 256)
            atomicAdd(&h[edst[i] / BSZ], 1);
        __syncthreads();
        bcnt[tid * NBUK + b] = h[tid];
    } else {                                 // prep work, concurrent
        prep_body(b - NBUK, tid, x, xbf, w1_rel, w1_root, w2_rel, w2_root,
                  w3_rel, w3_root, pL1, pL2, pL3, w4_rel, w4_root, b4, head_w,
                  wr, wt, cbuf);
    }
}

// ---------------- scan1 + workspace zeroing (fused, independent ranges) ------

__global__ void scanzero_kernel(int* __restrict__ a, int* __restrict__ bsum, int n,
                                float4* __restrict__ zb, int zn16) {
    __shared__ int buf[256];
    int tid = threadIdx.x, b = blockIdx.x;
    if (b < NBUK) {                          // per-row local exclusive scan
        int i = b * 256 + tid;
        int v = (i < n) ? a[i] : 0;
        buf[tid] = v;
        __syncthreads();
        #pragma unroll
        for (int off = 1; off < 256; off <<= 1) {
            int t = (tid >= off) ? buf[tid - off] : 0;
            __syncthreads();
            buf[tid] += t;
            __syncthreads();
        }
        if (i < n) a[i] = buf[tid] - v;      // local exclusive (in-place)
        if (tid == 255) bsum[b] = buf[255];  // RAW row total (scan moved to consumers)
    } else {                                 // zero gsum/cnt/sbuf/tbuf region
        float4 zero = make_float4(0.f, 0.f, 0.f, 0.f);
        for (int i = (b - NBUK) * 256 + tid; i < zn16; i += ZNB * 256) zb[i] = zero;
    }
}

// ---------------- MFMA GEMM v5 body (LDS passed in by caller) ----------------

template<int KS, int NT, int NHALF, int ST, int KCH>
__device__ void gemm_body(
    unsigned short* sB, unsigned short* sA, int i,
    const unsigned short* __restrict__ A, const unsigned short* __restrict__ Wall,
    const float* __restrict__ bias, unsigned short* __restrict__ OUT,
    int ldo, int ocol0, int relu, int N,
    const float* __restrict__ wrp, const float* __restrict__ wtp,
    float* __restrict__ sb, float* __restrict__ tb)
{
    const int K = KS * 16;                  // elements (shorts) per row
    const int CPC = KCH * 2;                // 16B chunks per row per A-chunk

    int chunk = i / (8 * NHALF);
    int rem = i - chunk * (8 * NHALF);
    int halfsel = rem >> 3;
    int rowb = chunk * 8 + (rem & 7);       // halves of a rowb share blockIdx%8
    int rbase = rowb * 128;
    if (rbase >= N) return;                 // uniform per block

    int tid = threadIdx.x;
    int wave = tid >> 6, lane = tid & 63;
    int l32 = lane & 31, half = lane >> 5;
    const unsigned short* W = Wall + (size_t)halfsel * NT * KS * 512;

    // stage B once (linear)
    #pragma unroll
    for (int j = 0; j < NT * KS * 64 / 256; j++) {
        int p = j * 256 + wave * 64;        // wave-uniform base unit
        dma16(W + ((size_t)p + lane) * 8, sB + (size_t)p * 8);
    }

    f32x16 acc[NT];
    #pragma unroll
    for (int t = 0; t < NT; t++)
        #pragma unroll
        for (int r = 0; r < 16; r++) acc[t][r] = 0.f;

    int lr = wave * 32 + l32;               // local row of this lane's A frags

    for (int kb = 0; kb < KS; kb += KCH) {
        if (kb > 0) __syncthreads();        // protect sA overwrite
        // stage A chunk: 128 rows x KCH ks, XOR-swizzled 16B chunks
        #pragma unroll
        for (int j = 0; j < 128 * CPC / 256; j++) {
            int p = j * 256 + wave * 64 + lane;
            int r = p / CPC;
            int c = p - r * CPC;
            int cg = c ^ (r & (CPC - 1));
            dma16(A + (size_t)(rbase + r) * K + kb * 16 + cg * 8,
                  sA + (size_t)(j * 256 + wave * 64) * 8);
        }
        __syncthreads();                    // drains vmcnt before barrier
        #pragma unroll
        for (int l = 0; l < KCH; l++) {
            int cs = (l * 2 + half) ^ (lr & (CPC - 1));
            bf16x8 a = *(const bf16x8*)(sA + (size_t)lr * (KCH * 16) + cs * 8);
            int ks = kb + l;
            #pragma unroll
            for (int t = 0; t < NT; t++) {
                bf16x8 b = *(const bf16x8*)(sB + ((size_t)(t * KS + ks) * 64 + lane) * 8);
                acc[t] = __builtin_amdgcn_mfma_f32_32x32x16_bf16(a, b, acc[t], 0, 0, 0);
            }
        }
    }

    int wrbase = rbase + wave * 32;
    if constexpr (ST) {
        // fused L4 projection: partial s/t per row via shfl reduce + atomicAdd
        #pragma unroll
        for (int reg = 0; reg < 16; reg++) {
            int row = wrbase + (reg & 3) + 8 * (reg >> 2) + 4 * half;
            float sv = 0.f, tv = 0.f;
            #pragma unroll
            for (int t = 0; t < NT; t++) {
                int col = halfsel * NT * 32 + t * 32 + l32;
                float v = fmaxf(acc[t][reg] + bias[col], 0.f);
                sv = fmaf(v, wrp[col], sv);
                tv = fmaf(v, wtp[col], tv);
            }
            #pragma unroll
            for (int m = 1; m < 32; m <<= 1) {
                sv += __shfl_xor(sv, m, 64);
                tv += __shfl_xor(tv, m, 64);
            }
            if (l32 == 0 && row < N) {
                atomicAdd(&sb[row], sv);
                atomicAdd(&tb[row], tv);
            }
        }
    } else {
        #pragma unroll
        for (int t = 0; t < NT; t++) {
            int col = halfsel * (NT * 32) + t * 32 + l32;   // halfsel-aware (R24)
            float bi = bias ? bias[col] : 0.f;
            #pragma unroll
            for (int reg = 0; reg < 16; reg++) {
                int row = wrbase + (reg & 3) + 8 * (reg >> 2) + 4 * half;
                if (row < N) {
                    float v = acc[t][reg] + bi;
                    if (relu) v = fmaxf(v, 0.f);
                    OUT[(size_t)row * ldo + ocol0 + col] = f2bf(v);
                }
            }
        }
    }
}

// standalone GEMM kernel (L2, L3+L4)
template<int KS, int NT, int NHALF, int ST, int KCH>
__global__ __launch_bounds__(256) void gemm_v5(
    const unsigned short* __restrict__ A, const unsigned short* __restrict__ Wall,
    const float* __restrict__ bias, unsigned short* __restrict__ OUT,
    int ldo, int ocol0, int relu, int N,
    const float* __restrict__ wrp, const float* __restrict__ wtp,
    float* __restrict__ sb, float* __restrict__ tb)
{
    __shared__ __align__(16) unsigned short sB[NT * KS * 512];
    __shared__ __align__(16) unsigned short sA[128 * KCH * 16];
    gemm_body<KS, NT, NHALF, ST, KCH>(sB, sA, blockIdx.x, A, Wall, bias, OUT,
                                      ldo, ocol0, relu, N, wrp, wtp, sb, tb);
}

// ---------------- partition + gemm1(first half), fused block ranges ----------
// partition block: exclusive-scans raw bucket totals in LDS (replaces scan2);
// block 0 stores the scanned offsets for build. LDS overlaid with gemm's 64KB.

__global__ void __launch_bounds__(256) partgemm_kernel(
    const int* __restrict__ src, const int* __restrict__ dst,
    const int* __restrict__ cnt, const int* __restrict__ braw,
    int* __restrict__ sbsum, unsigned long long* __restrict__ pedge,
    const unsigned short* __restrict__ A, const unsigned short* __restrict__ W,
    unsigned short* __restrict__ OUT, int N)
{
    __shared__ __align__(16) unsigned short smem[32768];   // 64KB, overlaid
    int tid = threadIdx.x, b = blockIdx.x;
    if (b < NBUK) {
        int* lbase = (int*)smem;             // 256 ints
        int* sscan = lbase + 256;            // 256 ints
        int v = braw[tid];
        sscan[tid] = v;
        __syncthreads();
        #pragma unroll
        for (int off = 1; off < 256; off <<= 1) {
            int t = (tid >= off) ? sscan[tid - off] : 0;
            __syncthreads();
            sscan[tid] += t;
            __syncthreads();
        }
        int ex = sscan[tid] - v;             // exclusive bucket offset
        if (b == 0) sbsum[tid] = ex;         // for build_kernel
        lbase[tid] = cnt[tid * NBUK + b] + ex;
        __syncthreads();
        int end = (b + 1) * EPB;
        for (int i = b * EPB + tid; i < end; i += 256) {
            int s = src[i], d = dst[i];
            int pos = atomicAdd(&lbase[d / BSZ], 1);
            pedge[pos] = (unsigned long long)(unsigned)s | ((unsigned long long)(unsigned)d << 32);
        }
    } else {
        gemm_body<8, 2, 2, 0, 8>(smem, smem + 16384, b - NBUK,
                                 A, W, nullptr, OUT, 128, 0, 0, N,
                                 nullptr, nullptr, nullptr, nullptr);
    }
}

// ---------------- build + gemm1(second half), fused block ranges -------------

__global__ void __launch_bounds__(256) buildgemm_kernel(
    const unsigned long long* __restrict__ pedge, const int* __restrict__ sbsum,
    int* __restrict__ rp, int* __restrict__ csr,
    const unsigned short* __restrict__ A, const unsigned short* __restrict__ W,
    unsigned short* __restrict__ OUT, int N)
{
    __shared__ __align__(16) unsigned short smem[32768];   // 64KB, overlaid
    int tid = threadIdx.x, b = blockIdx.x;
    if (b < NBUK) {
        int* sdeg  = (int*)smem;
        int* sc    = sdeg + 256;
        int* sbase = sc + 256;
        int* sfill = sbase + 256;
        int node0 = b * BSZ;
        int ncnt = NNODES - node0;
        if (ncnt > BSZ) ncnt = BSZ;
        if (ncnt < 0) ncnt = 0;
        int seg0 = sbsum[b];
        int seg1 = (b + 1 < NBUK) ? sbsum[b + 1] : NEDGES;
        sdeg[tid] = 0;
        sfill[tid] = 0;
        __syncthreads();
        for (int i = seg0 + tid; i < seg1; i += 256)
            atomicAdd(&sdeg[(int)(pedge[i] >> 32) - node0], 1);
        __syncthreads();
        sc[tid] = sdeg[tid];
        __syncthreads();
        #pragma unroll
        for (int off = 1; off < 256; off <<= 1) {
            int t = (tid >= off) ? sc[tid - off] : 0;
            __syncthreads();
            sc[tid] += t;
            __syncthreads();
        }
        sbase[tid] = sc[tid] - sdeg[tid];    // exclusive within bucket
        if (tid < ncnt) rp[node0 + tid] = seg0 + sbase[tid];
        if (b == NBUK - 1 && tid == 0) rp[NNODES] = NEDGES;
        __syncthreads();
        for (int i = seg0 + tid; i < seg1; i += 256) {
            unsigned long long p = pedge[i];
            int d = (int)(p >> 32) - node0;
            int pos = atomicAdd(&sfill[d], 1);
            csr[seg0 + sbase[d] + pos] = (int)(p & 0xffffffffu);
        }
    } else {
        gemm_body<8, 2, 2, 0, 8>(smem, smem + 16384, GB_SPLIT + (b - NBUK),
                                 A, W, nullptr, OUT, 128, 0, 0, N,
                                 nullptr, nullptr, nullptr, nullptr);
    }
}

// ---------------- bf16 neighbor-sum via CSR gather (R17 exact) ---------------

__device__ __forceinline__ void acc8(float* a, uint4 u) {
    a[0] += bf2f(u.x & 0xffffu); a[1] += bf2f(u.x >> 16);
    a[2] += bf2f(u.y & 0xffffu); a[3] += bf2f(u.y >> 16);
    a[4] += bf2f(u.z & 0xffffu); a[5] += bf2f(u.z >> 16);
    a[6] += bf2f(u.w & 0xffffu); a[7] += bf2f(u.w >> 16);
}

template<int LPF, int SUBS>
__global__ void agg_kernel_v4(const unsigned short* __restrict__ X, int ldx,
                              const int* __restrict__ rp, const int* __restrict__ csr,
                              const unsigned short* __restrict__ root, int ldr,
                              const float* __restrict__ bias, int relu,
                              unsigned short* __restrict__ OUT, int ldo, int N) {
    int t = blockIdx.x * blockDim.x + threadIdx.x;
    int node = t / (SUBS * LPF);
    int r = t % (SUBS * LPF);
    int sub = r / LPF;
    int sl = r % LPF;
    if (node >= N) return;
    float a[8] = {0.f, 0.f, 0.f, 0.f, 0.f, 0.f, 0.f, 0.f};
    int e0 = rp[node], e1 = rp[node + 1];
    const unsigned short* xb = X + 8 * sl;
    int e = e0 + sub;
    for (; e + 3 * SUBS < e1; e += 4 * SUBS) {    // 4 independent gathers in flight
        int s0 = csr[e], s1 = csr[e + SUBS], s2 = csr[e + 2 * SUBS], s3 = csr[e + 3 * SUBS];
        uint4 u0 = *(const uint4*)(xb + (size_t)s0 * ldx);
        uint4 u1 = *(const uint4*)(xb + (size_t)s1 * ldx);
        uint4 u2 = *(const uint4*)(xb + (size_t)s2 * ldx);
        uint4 u3 = *(const uint4*)(xb + (size_t)s3 * ldx);
        acc8(a, u0); acc8(a, u1); acc8(a, u2); acc8(a, u3);
    }
    for (; e < e1; e += SUBS) {
        uint4 u = *(const uint4*)(xb + (size_t)csr[e] * ldx);
        acc8(a, u);
    }
    #pragma unroll
    for (int m = LPF; m < SUBS * LPF; m <<= 1)
        #pragma unroll
        for (int i = 0; i < 8; i++) a[i] += __shfl_xor(a[i], m, 64);
    if (sub == 0) {
        if (root) {
            uint4 u = *(const uint4*)(root + (size_t)node * ldr + 8 * sl);
            acc8(a, u);
        }
        if (bias) {
            float4 b0 = *(const float4*)(bias + 8 * sl);
            float4 b1 = *(const float4*)(bias + 8 * sl + 4);
            a[0] += b0.x; a[1] += b0.y; a[2] += b0.z; a[3] += b0.w;
            a[4] += b1.x; a[5] += b1.y; a[6] += b1.z; a[7] += b1.w;
        }
        if (relu) {
            #pragma unroll
            for (int i = 0; i < 8; i++) a[i] = fmaxf(a[i], 0.f);
        }
        uint4 o;
        o.x = (unsigned)f2bf(a[0]) | ((unsigned)f2bf(a[1]) << 16);
        o.y = (unsigned)f2bf(a[2]) | ((unsigned)f2bf(a[3]) << 16);
        o.z = (unsigned)f2bf(a[4]) | ((unsigned)f2bf(a[5]) << 16);
        o.w = (unsigned)f2bf(a[6]) | ((unsigned)f2bf(a[7]) << 16);
        *(uint4*)(OUT + (size_t)node * ldo + 8 * sl) = o;
    }
}

// ---------------- pool + head (R17 shape) ------------------------------------

__global__ void aggpool_kernel(const float* __restrict__ s, const float* __restrict__ t,
                               const int* __restrict__ rp, const int* __restrict__ csr,
                               const int* __restrict__ batch, float* __restrict__ gsum,
                               int* __restrict__ cnt, int N) {
    __shared__ float ls[NGRAPH];
    __shared__ int lc[NGRAPH];
    int tid = threadIdx.x;
    if (tid < NGRAPH) { ls[tid] = 0.f; lc[tid] = 0; }
    __syncthreads();
    int n = blockIdx.x * blockDim.x + tid;
    if (n < N) {
        float a = 0.f;
        int e = rp[n], e1 = rp[n + 1];
        for (; e + 3 < e1; e += 4) {
            int s0 = csr[e], s1 = csr[e + 1], s2 = csr[e + 2], s3 = csr[e + 3];
            a += s[s0] + s[s1] + s[s2] + s[s3];
        }
        for (; e < e1; e++) a += s[csr[e]];
        int g = batch[n];
        atomicAdd(&ls[g], a + t[n]);
        atomicAdd(&lc[g], 1);
    }
    __syncthreads();
    if (tid < NGRAPH && lc[tid] > 0) {
        atomicAdd(&gsum[tid], ls[tid]);
        atomicAdd(&cnt[tid], lc[tid]);
    }
}

__global__ void final_kernel(const float* __restrict__ gsum, const int* __restrict__ cnt,
                             const float* __restrict__ cbuf, const float* __restrict__ head_b,
                             float* __restrict__ out) {
    int g = threadIdx.x;
    if (g < NGRAPH) {
        float c = (float)(cnt[g] > 0 ? cnt[g] : 1);
        out[g] = gsum[g] / c + cbuf[0] + head_b[0];
    }
}

// ---------------- launch ----------------

extern "C" void kernel_launch(void* const* d_in, const int* in_sizes, int n_in,
                              void* d_out, int out_size, void* d_ws, size_t ws_size,
                              hipStream_t stream) {
    const float* x       = (const float*)d_in[0];
    const int*   edge    = (const int*)d_in[1];
    const int*   batch   = (const int*)d_in[2];
    const float* w1_rel  = (const float*)d_in[3];
    const float* w1_root = (const float*)d_in[4];
    const float* b1      = (const float*)d_in[5];
    const float* w2_rel  = (const float*)d_in[6];
    const float* w2_root = (const float*)d_in[7];
    const float* b2      = (const float*)d_in[8];
    const float* w3_rel  = (const float*)d_in[9];
    const float* w3_root = (const float*)d_in[10];
    const float* b3      = (const float*)d_in[11];
    const float* w4_rel  = (const float*)d_in[12];
    const float* w4_root = (const float*)d_in[13];
    const float* b4      = (const float*)d_in[14];
    const float* head_w  = (const float*)d_in[15];
    const float* head_b  = (const float*)d_in[16];
    float* out = (float*)d_out;

    const int N = NNODES, E = NEDGES;
    const int* esrc = edge;
    const int* edst = edge + E;

    char* ws = (char*)d_ws;
    size_t off = 0;
    auto alloc = [&](size_t bytes) -> char* {
        char* p = ws + off;
        off = (off + bytes + 255) & ~(size_t)255;
        return p;
    };
    // zeroed region first (one fused zeroing pass): gsum, cnt, sbuf, tbuf
    float* gsum  = (float*)alloc(NGRAPH * 4);
    int*   cnt   = (int*)alloc(NGRAPH * 4);
    float* sbuf  = (float*)alloc((size_t)N * 4);
    float* tbuf  = (float*)alloc((size_t)N * 4);
    size_t zero_bytes = off;                               // 256-aligned, /16 ok
    int*   bcnt  = (int*)alloc((size_t)NBUK * NBUK * 4);   // bucket x block counts
    int*   bsum  = (int*)alloc(256 * 4);                   // RAW bucket totals
    int*   sbsum = (int*)alloc(256 * 4);                   // scanned bucket offsets
    int*   rp    = (int*)alloc((size_t)(N + 1) * 4);
    int*   csr   = (int*)alloc((size_t)E * 4);
    unsigned long long* pedge = (unsigned long long*)alloc((size_t)E * 8);
    unsigned short* xbf    = (unsigned short*)alloc((size_t)N * 128 * 2);
    unsigned short* z1     = (unsigned short*)alloc((size_t)N * 128 * 2);  // [x@w1_rel | x@w1_root]
    unsigned short* combo2 = (unsigned short*)alloc((size_t)N * 128 * 2);  // [agg2 | h1]
    unsigned short* combo3 = (unsigned short*)alloc((size_t)N * 256 * 2);  // [agg3 | h2]
    unsigned short* pL1    = (unsigned short*)alloc(4 * 8 * 512 * 2);      // also DMA overrun slack
    unsigned short* pL2    = (unsigned short*)alloc(4 * 8 * 512 * 2);
    unsigned short* pL3    = (unsigned short*)alloc(6 * 16 * 512 * 2);
    float* wr    = (float*)alloc(192 * 4);
    float* wt    = (float*)alloc(192 * 4);
    float* cbuf  = (float*)alloc(4);
    (void)ws_size;

    const int TB = 256;

    // CSR build + prep; gemm1 (784 half-blocks) overlapped with partition/build
    histprep_kernel<<<NBUK + PREP_NB, 256, 0, stream>>>(
        edst, bcnt, x, xbf, w1_rel, w1_root, w2_rel, w2_root, w3_rel, w3_root,
        pL1, pL2, pL3, w4_rel, w4_root, b4, head_w, wr, wt, cbuf);
    scanzero_kernel<<<NBUK + ZNB, 256, 0, stream>>>(
        bcnt, bsum, NBUK * NBUK, (float4*)ws, (int)(zero_bytes / 16));
    partgemm_kernel<<<NBUK + GB_SPLIT, 256, 0, stream>>>(
        esrc, edst, bcnt, bsum, sbsum, pedge, xbf, pL1, z1, N);
    buildgemm_kernel<<<NBUK + (RCHUNK * 8 * 2 - GB_SPLIT), 256, 0, stream>>>(
        pedge, sbsum, rp, csr, xbf, pL1, z1, N);

    // h1 = relu( nbrsum(z1[:,:64]) + z1[:,64:] + b1 ) -> combo2[:,64:]
    agg_kernel_v4<8, 2><<<(N * 16 + TB - 1) / TB, TB, 0, stream>>>(z1, 128, rp, csr,
                                                                   z1 + 64, 128, b1, 1, combo2 + 64, 128, N);
    // agg2 = nbrsum(h1) -> combo2[:,:64]
    agg_kernel_v4<8, 2><<<(N * 16 + TB - 1) / TB, TB, 0, stream>>>(combo2 + 64, 128, rp, csr,
                                                                   nullptr, 0, nullptr, 0, combo2, 128, N);
    // L2: h2 = relu(combo2 @ [w2_rel; w2_root] + b2) -> combo3[:,128:]
    // col-halved: 48KB LDS -> 3 blocks/CU, 784 blocks = one full round
    gemm_v5<8, 2, 2, 0, 8><<<RCHUNK * 8 * 2, 256, 0, stream>>>(
        combo2, pL2, b2, combo3, 256, 128, 1, N, nullptr, nullptr, nullptr, nullptr);
    // agg3 = nbrsum(h2) -> combo3[:,:128]
    agg_kernel_v4<16, 2><<<(N * 32 + TB - 1) / TB, TB, 0, stream>>>(combo3 + 128, 256, rp, csr,
                                                                    nullptr, 0, nullptr, 0, combo3, 256, N);
    // L3 + fused L4 projection (K=256, col-halved, A chunked 16KB, LDS 64KB)
    gemm_v5<16, 3, 2, 1, 4><<<RCHUNK * 8 * 2, 256, 0, stream>>>(
        combo3, pL3, b3, nullptr, 0, 0, 0, N, wr, wt, sbuf, tbuf);

    // pool + head
    aggpool_kernel<<<(N + TB - 1) / TB, TB, 0, stream>>>(sbuf, tbuf, rp, csr, batch, gsum, cnt, N);
    final_kernel<<<1, 64, 0, stream>>>(gsum, cnt, cbuf, head_b, out);
}